// Round 4
// baseline (2998.116 us; speedup 1.0000x reference)
//
#include <hip/hip_runtime.h>
#include <hip/hip_bf16.h>

// Problem constants (static: B=4, Q0=1000, D=256, NH=8, HD=32, FF=1024, L=6, NL=4, NP=4)
// Inputs: fp32. Outputs: fp32.
// MHA/top-k NUMERICS CONTRACT: every per-query reduction chain (dot c-order, online-softmax
// j-order, GEMM k-order) must keep the exact sequential FP ordering — top-k set selection
// flips under ~1e-6 perturbations. R1 LESSON: redistributing the MHA DAG across lanes broke
// bits. Only load-source/load-width/scheduling changes with IDENTICAL expression text are safe.
// R4: (a) k_mha drops LDS staging entirely — K/V read straight from global with wave-uniform
// addresses (compiler scalarizes to s_load / broadcast VMEM). Pure load-source change; all
// chain expressions byte-identical to R3 (which passed). Probes the LDS-broadcast-throughput
// theory for the ~900cyc/key wall. (b) FFN1 GEMM 128x128 tile, 8x8 microtile (k-order exact).
#define BB 4
#define DD 256

typedef unsigned long long u64;
typedef long long s64;
typedef unsigned int u32;

__device__ __forceinline__ float sigm(float x) { return 1.0f / (1.0f + expf(-x)); }

// ---------------- LayerNorm (D=256, one row per block of 256 threads) ----------------
__global__ void k_ln(const float* __restrict__ x, const float* __restrict__ w,
                     const float* __restrict__ b, float* __restrict__ ln) {
    int row = blockIdx.x, tid = threadIdx.x;
    float v = x[(size_t)row * DD + tid];
    __shared__ float sred[4];
    float s = v;
#pragma unroll
    for (int o = 32; o > 0; o >>= 1) s += __shfl_down(s, o);
    if ((tid & 63) == 0) sred[tid >> 6] = s;
    __syncthreads();
    float mu = (sred[0] + sred[1] + sred[2] + sred[3]) * (1.0f / 256.0f);
    __syncthreads();
    float d = v - mu;
    float s2 = d * d;
#pragma unroll
    for (int o = 32; o > 0; o >>= 1) s2 += __shfl_down(s2, o);
    if ((tid & 63) == 0) sred[tid >> 6] = s2;
    __syncthreads();
    float var = (sred[0] + sred[1] + sred[2] + sred[3]) * (1.0f / 256.0f);
    float r = rsqrtf(var + 1e-5f);
    ln[(size_t)row * DD + tid] = d * r * w[tid] + b[tid];
}

// ---------------- GEMM core: C[M,N] = act((A+Pe)[M,K] @ W[N,K]^T + bias) (+ residual) ----------
// 64x64 tile, BK=16, 256 threads, 4x4 microtile, double-buffered LDS (1 barrier/iter).
// Per-output-element chain: strict ascending-k single-fma (acc += a*w) — bit-identical to R0.
template <int ACT, int RES>
__device__ __forceinline__ void gemm_core(float (*As)[16][64], float (*Ws)[16][64],
                                          const float* __restrict__ A, const float* __restrict__ Pe, int pe,
                                          const float* __restrict__ W, const float* __restrict__ bias,
                                          const float* __restrict__ Rm, float* __restrict__ C,
                                          float* __restrict__ C2,
                                          int M, int N, int K, int row0, int col0) {
    int tid = threadIdx.x;
    int tx = tid & 15, ty = tid >> 4;
    int lm = tid >> 2, lk = (tid & 3) * 4;
    float acc[4][4] = {{0.f}};
    int ar = row0 + lm;
    const float* Arow = A + (size_t)ar * K + lk;
    const float* Prow = pe ? (Pe + (size_t)ar * K + lk) : nullptr;
    const float* Wrow = W + (size_t)(col0 + lm) * K + lk;  // N multiple of 64
    float4 av = make_float4(0.f, 0.f, 0.f, 0.f), wv;
    if (ar < M) {
        av = *(const float4*)(Arow);
        if (pe) { float4 pv = *(const float4*)(Prow); av.x += pv.x; av.y += pv.y; av.z += pv.z; av.w += pv.w; }
    }
    wv = *(const float4*)(Wrow);
    As[0][lk + 0][lm] = av.x; As[0][lk + 1][lm] = av.y; As[0][lk + 2][lm] = av.z; As[0][lk + 3][lm] = av.w;
    Ws[0][lk + 0][lm] = wv.x; Ws[0][lk + 1][lm] = wv.y; Ws[0][lk + 2][lm] = wv.z; Ws[0][lk + 3][lm] = wv.w;
    __syncthreads();
    int nb = K >> 4;
    for (int t = 0; t < nb; t++) {
        int cur = t & 1, nxt = cur ^ 1;
        bool more = (t + 1 < nb);
        if (more) {
            int k0 = (t + 1) << 4;
            av = make_float4(0.f, 0.f, 0.f, 0.f);
            if (ar < M) {
                av = *(const float4*)(Arow + k0);
                if (pe) { float4 pv = *(const float4*)(Prow + k0); av.x += pv.x; av.y += pv.y; av.z += pv.z; av.w += pv.w; }
            }
            wv = *(const float4*)(Wrow + k0);
        }
#pragma unroll
        for (int kk = 0; kk < 16; kk++) {
            float4 a = *(const float4*)&As[cur][kk][ty << 2];
            float4 w = *(const float4*)&Ws[cur][kk][tx << 2];
            acc[0][0] += a.x * w.x; acc[0][1] += a.x * w.y; acc[0][2] += a.x * w.z; acc[0][3] += a.x * w.w;
            acc[1][0] += a.y * w.x; acc[1][1] += a.y * w.y; acc[1][2] += a.y * w.z; acc[1][3] += a.y * w.w;
            acc[2][0] += a.z * w.x; acc[2][1] += a.z * w.y; acc[2][2] += a.z * w.z; acc[2][3] += a.z * w.w;
            acc[3][0] += a.w * w.x; acc[3][1] += a.w * w.y; acc[3][2] += a.w * w.z; acc[3][3] += a.w * w.w;
        }
        if (more) {
            As[nxt][lk + 0][lm] = av.x; As[nxt][lk + 1][lm] = av.y; As[nxt][lk + 2][lm] = av.z; As[nxt][lk + 3][lm] = av.w;
            Ws[nxt][lk + 0][lm] = wv.x; Ws[nxt][lk + 1][lm] = wv.y; Ws[nxt][lk + 2][lm] = wv.z; Ws[nxt][lk + 3][lm] = wv.w;
        }
        __syncthreads();
    }
#pragma unroll
    for (int i2 = 0; i2 < 4; i2++) {
        int r = row0 + (ty << 2) + i2;
        if (r >= M) continue;
        int cc = col0 + (tx << 2);
        float4 v;
        v.x = acc[i2][0] + bias[cc + 0];
        v.y = acc[i2][1] + bias[cc + 1];
        v.z = acc[i2][2] + bias[cc + 2];
        v.w = acc[i2][3] + bias[cc + 3];
        if (ACT == 1) { v.x = fmaxf(v.x, 0.f); v.y = fmaxf(v.y, 0.f); v.z = fmaxf(v.z, 0.f); v.w = fmaxf(v.w, 0.f); }
        if (RES == 1) {
            float4 rm = *(const float4*)(Rm + (size_t)r * N + cc);
            v.x += rm.x; v.y += rm.y; v.z += rm.z; v.w += rm.w;
        }
        *(float4*)(C + (size_t)r * N + cc) = v;
        if (C2) *(float4*)(C2 + (size_t)r * N + cc) = v;
    }
}

template <int ACT, int RES, int PE>
__global__ __launch_bounds__(256) void k_gemm(const float* __restrict__ A, const float* __restrict__ Pe,
                                              const float* __restrict__ W, const float* __restrict__ bias,
                                              const float* __restrict__ Rm, float* __restrict__ C,
                                              int M, int N, int K) {
    __shared__ float As[2][16][64];
    __shared__ float Ws[2][16][64];
    gemm_core<ACT, RES>(As, Ws, A, Pe, PE, W, bias, Rm, C, nullptr, M, N, K, blockIdx.y * 64, blockIdx.x * 64);
}

// FFN second GEMM with fused layer-output store (C2 = outf region; same values as C).
__global__ __launch_bounds__(256) void k_gemm_st2(const float* __restrict__ A, const float* __restrict__ W,
                                                  const float* __restrict__ bias, const float* __restrict__ Rm,
                                                  float* __restrict__ C, float* __restrict__ C2,
                                                  int M, int N, int K) {
    __shared__ float As[2][16][64];
    __shared__ float Ws[2][16][64];
    gemm_core<0, 1>(As, Ws, A, nullptr, 0, W, bias, Rm, C, C2, M, N, K, blockIdx.y * 64, blockIdx.x * 64);
}

// QKV merged: blockIdx.z in {0,1,2} picks weight block / bias / output; z<2 adds Pe.
__global__ __launch_bounds__(256) void k_gemm_qkv(const float* __restrict__ A, const float* __restrict__ Pe,
                                                  const float* __restrict__ Wqkv, const float* __restrict__ bqkv,
                                                  float* __restrict__ Cq, float* __restrict__ Ck, float* __restrict__ Cv,
                                                  int M, int K) {
    __shared__ float As[2][16][64];
    __shared__ float Ws[2][16][64];
    int z = blockIdx.z;
    const float* W = Wqkv + (size_t)z * 256 * K;
    const float* bias = bqkv + z * 256;
    float* C = (z == 0) ? Cq : (z == 1) ? Ck : Cv;
    gemm_core<0, 0>(As, Ws, A, Pe, (z < 2) ? 1 : 0, W, bias, nullptr, C, nullptr, M, 256, K,
                    blockIdx.y * 64, blockIdx.x * 64);
}

// off (N=256) + aw (N=128) merged: z picks; z=1 blocks with col0>=128 exit whole-block.
__global__ __launch_bounds__(256) void k_gemm_offaw(const float* __restrict__ A, const float* __restrict__ Pe,
                                                    const float* __restrict__ Woff, const float* __restrict__ boff,
                                                    const float* __restrict__ Waw, const float* __restrict__ baw,
                                                    float* __restrict__ Coff, float* __restrict__ Caw,
                                                    int M, int K) {
    __shared__ float As[2][16][64];
    __shared__ float Ws[2][16][64];
    int z = blockIdx.z;
    int N = (z == 0) ? 256 : 128;
    if ((int)(blockIdx.x * 64) >= N) return;  // uniform whole-block exit (before any barrier)
    gemm_core<0, 0>(As, Ws, A, Pe, 1, (z == 0) ? Woff : Waw, (z == 0) ? boff : baw, nullptr,
                    (z == 0) ? Coff : Caw, nullptr, M, N, K, blockIdx.y * 64, blockIdx.x * 64);
}

// ---------------- FFN1 GEMM: 128x128 tile, BK=16, 256 threads, 8x8 microtile ----------------
// N=1024, K=256 static. ReLU epilogue. Per-output chain: strict ascending-k single-fma —
// bit-identical to the 64x64 version (only the thread->output mapping changes).
// Column/row microtile split tx*4 / 64+tx*4 keeps LDS reads at 2-way (free) aliasing.
__global__ __launch_bounds__(256) void k_ff1(const float* __restrict__ A, const float* __restrict__ W,
                                             const float* __restrict__ bias, float* __restrict__ C, int M) {
    const int K = 256;
    __shared__ float As[2][16][128];
    __shared__ float Ws[2][16][128];
    int tid = threadIdx.x;
    int tx = tid & 15, ty = tid >> 4;
    int row0 = blockIdx.y * 128, col0 = blockIdx.x * 128;
    int lm = tid >> 1, lk = (tid & 1) * 8;
    float acc[8][8] = {{0.f}};
    int ar = row0 + lm;
    const float* Arow = A + (size_t)ar * K + lk;
    const float* Wrow = W + (size_t)(col0 + lm) * K + lk;
    float4 a0 = make_float4(0.f, 0.f, 0.f, 0.f), a1 = a0, w0, w1;
    if (ar < M) { a0 = *(const float4*)(Arow); a1 = *(const float4*)(Arow + 4); }
    w0 = *(const float4*)(Wrow); w1 = *(const float4*)(Wrow + 4);
    As[0][lk + 0][lm] = a0.x; As[0][lk + 1][lm] = a0.y; As[0][lk + 2][lm] = a0.z; As[0][lk + 3][lm] = a0.w;
    As[0][lk + 4][lm] = a1.x; As[0][lk + 5][lm] = a1.y; As[0][lk + 6][lm] = a1.z; As[0][lk + 7][lm] = a1.w;
    Ws[0][lk + 0][lm] = w0.x; Ws[0][lk + 1][lm] = w0.y; Ws[0][lk + 2][lm] = w0.z; Ws[0][lk + 3][lm] = w0.w;
    Ws[0][lk + 4][lm] = w1.x; Ws[0][lk + 5][lm] = w1.y; Ws[0][lk + 6][lm] = w1.z; Ws[0][lk + 7][lm] = w1.w;
    __syncthreads();
    const int nb = K >> 4;  // 16
    for (int t = 0; t < nb; t++) {
        int cur = t & 1, nxt = cur ^ 1;
        bool more = (t + 1 < nb);
        if (more) {
            int k0 = (t + 1) << 4;
            a0 = make_float4(0.f, 0.f, 0.f, 0.f); a1 = a0;
            if (ar < M) { a0 = *(const float4*)(Arow + k0); a1 = *(const float4*)(Arow + k0 + 4); }
            w0 = *(const float4*)(Wrow + k0); w1 = *(const float4*)(Wrow + k0 + 4);
        }
#pragma unroll
        for (int kk = 0; kk < 16; kk++) {
            float4 xa0 = *(const float4*)&As[cur][kk][ty * 4];
            float4 xa1 = *(const float4*)&As[cur][kk][64 + ty * 4];
            float4 xw0 = *(const float4*)&Ws[cur][kk][tx * 4];
            float4 xw1 = *(const float4*)&Ws[cur][kk][64 + tx * 4];
            float av8[8] = {xa0.x, xa0.y, xa0.z, xa0.w, xa1.x, xa1.y, xa1.z, xa1.w};
            float wv8[8] = {xw0.x, xw0.y, xw0.z, xw0.w, xw1.x, xw1.y, xw1.z, xw1.w};
#pragma unroll
            for (int i = 0; i < 8; i++)
#pragma unroll
                for (int j2 = 0; j2 < 8; j2++)
                    acc[i][j2] += av8[i] * wv8[j2];
        }
        if (more) {
            As[nxt][lk + 0][lm] = a0.x; As[nxt][lk + 1][lm] = a0.y; As[nxt][lk + 2][lm] = a0.z; As[nxt][lk + 3][lm] = a0.w;
            As[nxt][lk + 4][lm] = a1.x; As[nxt][lk + 5][lm] = a1.y; As[nxt][lk + 6][lm] = a1.z; As[nxt][lk + 7][lm] = a1.w;
            Ws[nxt][lk + 0][lm] = w0.x; Ws[nxt][lk + 1][lm] = w0.y; Ws[nxt][lk + 2][lm] = w0.z; Ws[nxt][lk + 3][lm] = w0.w;
            Ws[nxt][lk + 4][lm] = w1.x; Ws[nxt][lk + 5][lm] = w1.y; Ws[nxt][lk + 6][lm] = w1.z; Ws[nxt][lk + 7][lm] = w1.w;
        }
        __syncthreads();
    }
#pragma unroll
    for (int i = 0; i < 8; i++) {
        int r = row0 + ((i < 4) ? (ty * 4 + i) : (64 + ty * 4 + (i - 4)));
        if (r >= M) continue;
#pragma unroll
        for (int jh = 0; jh < 2; jh++) {
            int cc = col0 + jh * 64 + tx * 4;
            float4 v;
            v.x = fmaxf(acc[i][jh * 4 + 0] + bias[cc + 0], 0.f);
            v.y = fmaxf(acc[i][jh * 4 + 1] + bias[cc + 1], 0.f);
            v.z = fmaxf(acc[i][jh * 4 + 2] + bias[cc + 2], 0.f);
            v.w = fmaxf(acc[i][jh * 4 + 3] + bias[cc + 3], 0.f);
            *(float4*)(C + (size_t)r * 1024 + cc) = v;
        }
    }
}

// ---------------- MHA: sequential-key flash attention, HD=32, 1 query/thread ----------------
// R4: no LDS. K/V rows are read straight from global with wave-uniform addresses (only the
// key index + blockIdx vary) — the compiler scalarizes these to s_load / broadcast VMEM, so
// the LDS pipe is out of the loop entirely. Dot block pipelined one 8-key group ahead (R3).
// All chain expressions (dot c-order, j-ordered (m,l,acc) updates) are byte-identical to R3.
#define MHA_DOT8G(SREG, JJ)                                                      \
    {                                                                            \
        _Pragma("unroll")                                                        \
        for (int u = 0; u < 8; u++) SREG[u] = 0.f;                               \
        _Pragma("unroll")                                                        \
        for (int c4 = 0; c4 < 8; c4++) {                                         \
            float q0 = qv[c4 * 4 + 0], q1 = qv[c4 * 4 + 1];                      \
            float q2 = qv[c4 * 4 + 2], q3 = qv[c4 * 4 + 3];                      \
            _Pragma("unroll")                                                    \
            for (int u = 0; u < 8; u++) {                                        \
                float4 k4 = *(const float4*)(Kbase + (size_t)((JJ) + u) * DD + c4 * 4); \
                SREG[u] += q0 * k4.x; SREG[u] += q1 * k4.y;                      \
                SREG[u] += q2 * k4.z; SREG[u] += q3 * k4.w;                      \
            }                                                                    \
        }                                                                        \
    }

__global__ __launch_bounds__(64) void k_mha(const float* __restrict__ Qb, const float* __restrict__ Kb,
                                            const float* __restrict__ Vb, float* __restrict__ Ob, int Qn) {
    int bh = blockIdx.y;
    int b = bh >> 3, h = bh & 7;
    int lane = threadIdx.x;
    int qi = blockIdx.x * 64 + lane;
    const float* Kbase = Kb + (size_t)b * Qn * DD + h * 32;
    const float* Vbase = Vb + (size_t)b * Qn * DD + h * 32;
    float qv[32];
    float acc[32];
#pragma unroll
    for (int c = 0; c < 32; c++) acc[c] = 0.f;
    float m = -INFINITY, l = 0.f;
    const float scale = 0.17677669529663687f;  // 1/sqrt(32)
    bool active = qi < Qn;
    if (active) {
        const float4* qp = (const float4*)(Qb + ((size_t)(b * Qn + qi)) * DD + h * 32);
#pragma unroll
        for (int c4 = 0; c4 < 8; c4++) {
            float4 t = qp[c4];
            qv[c4 * 4 + 0] = t.x * scale; qv[c4 * 4 + 1] = t.y * scale;
            qv[c4 * 4 + 2] = t.z * scale; qv[c4 * 4 + 3] = t.w * scale;
        }
    } else {
#pragma unroll
        for (int c = 0; c < 32; c++) qv[c] = 0.f;
    }
    int ng = Qn >> 3;
    float scur[8], snxt[8];
    if (ng > 0) MHA_DOT8G(scur, 0)
    for (int g = 0; g < ng; g++) {
        int jj = g << 3;
        bool morep = (g + 1 < ng);
        if (morep) MHA_DOT8G(snxt, jj + 8)
#pragma unroll
        for (int u = 0; u < 8; u++) {
            float sv = scur[u];
            float mn = fmaxf(m, sv);
            float e = expf(fminf(m - sv, sv - m));  // the single non-trivial expf
            bool gt = sv > m;
            float sc = gt ? e : 1.0f;
            float p = gt ? 1.0f : e;
            l = l * sc + p;
            m = mn;
#pragma unroll
            for (int c4 = 0; c4 < 8; c4++) {
                float4 v4 = *(const float4*)(Vbase + (size_t)(jj + u) * DD + c4 * 4);
                acc[c4 * 4 + 0] = acc[c4 * 4 + 0] * sc + p * v4.x;
                acc[c4 * 4 + 1] = acc[c4 * 4 + 1] * sc + p * v4.y;
                acc[c4 * 4 + 2] = acc[c4 * 4 + 2] * sc + p * v4.z;
                acc[c4 * 4 + 3] = acc[c4 * 4 + 3] * sc + p * v4.w;
            }
        }
        if (morep) {
#pragma unroll
            for (int u = 0; u < 8; u++) scur[u] = snxt[u];
        }
    }
    for (int j = ng << 3; j < Qn; j++) {
        float sv = 0.f;
#pragma unroll
        for (int c4 = 0; c4 < 8; c4++) {
            float4 k4 = *(const float4*)(Kbase + (size_t)j * DD + c4 * 4);
            sv += qv[c4 * 4 + 0] * k4.x; sv += qv[c4 * 4 + 1] * k4.y;
            sv += qv[c4 * 4 + 2] * k4.z; sv += qv[c4 * 4 + 3] * k4.w;
        }
        float mn = fmaxf(m, sv);
        float e = expf(fminf(m - sv, sv - m));
        bool gt = sv > m;
        float sc = gt ? e : 1.0f;
        float p = gt ? 1.0f : e;
        l = l * sc + p;
        m = mn;
#pragma unroll
        for (int c4 = 0; c4 < 8; c4++) {
            float4 v4 = *(const float4*)(Vbase + (size_t)j * DD + c4 * 4);
            acc[c4 * 4 + 0] = acc[c4 * 4 + 0] * sc + p * v4.x;
            acc[c4 * 4 + 1] = acc[c4 * 4 + 1] * sc + p * v4.y;
            acc[c4 * 4 + 2] = acc[c4 * 4 + 2] * sc + p * v4.z;
            acc[c4 * 4 + 3] = acc[c4 * 4 + 3] * sc + p * v4.w;
        }
    }
    if (active) {
        float inv = 1.0f / l;
        float* op = Ob + ((size_t)(b * Qn + qi)) * DD + h * 32;
#pragma unroll
        for (int c4 = 0; c4 < 8; c4++) {
            float4 o;
            o.x = acc[c4 * 4 + 0] * inv; o.y = acc[c4 * 4 + 1] * inv;
            o.z = acc[c4 * 4 + 2] * inv; o.w = acc[c4 * 4 + 3] * inv;
            *(float4*)(op + c4 * 4) = o;
        }
    }
}

// ---------------- feature transpose: [b][c=256][H][W] -> [b][h][H*W][hd=32] ----------------
// Pure data movement (bit-exact). Coalesced reads (64-float runs) and writes (128B runs).
__global__ __launch_bounds__(256) void k_trfeat(const float* __restrict__ in, float* __restrict__ out, int HH) {
    __shared__ float t[32][65];
    int bh = blockIdx.y;             // b*8 + h
    int b = bh >> 3, h = bh & 7;
    int s0 = blockIdx.x * 64;
    int tid = threadIdx.x;
    const float* ip = in + ((size_t)(b * 256 + h * 32)) * HH + s0;
#pragma unroll
    for (int i = 0; i < 8; i++) {
        int idx = i * 256 + tid;
        int c = idx >> 6, s = idx & 63;
        t[c][s] = ip[(size_t)c * HH + s];
    }
    __syncthreads();
    float* op = out + ((size_t)bh * HH + s0) * 32;
#pragma unroll
    for (int i = 0; i < 8; i++) {
        int idx = i * 256 + tid;
        int s = idx >> 5, c = idx & 31;
        op[(size_t)s * 32 + c] = t[c][s];
    }
}

// ---------------- deformable sampling ----------------
__device__ __forceinline__ float d_samp(const float* fp, int W, int H, int x, int y) {
    if (x < 0 || x > W - 1 || y < 0 || y > H - 1) return 0.f;
    return fp[y * W + x];
}
__device__ __forceinline__ float d_bil(const float* fp, int W, int H, float gx, float gy) {
    float fx = (gx + 1.0f) * 0.5f * (float)(W - 1);
    float fy = (gy + 1.0f) * 0.5f * (float)(H - 1);
    float x0f = floorf(fx), y0f = floorf(fy);
    int x0 = (int)x0f, y0 = (int)y0f;
    float wx = fx - x0f, wy = fy - y0f;
    float v00 = d_samp(fp, W, H, x0, y0);
    float v10 = d_samp(fp, W, H, x0 + 1, y0);
    float v01 = d_samp(fp, W, H, x0, y0 + 1);
    float v11 = d_samp(fp, W, H, x0 + 1, y0 + 1);
    return v00 * (1.f - wx) * (1.f - wy) + v10 * wx * (1.f - wy) + v01 * (1.f - wx) * wy + v11 * wx * wy;
}
// stride-32 (transposed-layout) variants: identical arithmetic, only addressing differs.
__device__ __forceinline__ float d_samp32(const float* fp, int W, int H, int x, int y) {
    if (x < 0 || x > W - 1 || y < 0 || y > H - 1) return 0.f;
    return fp[(size_t)(y * W + x) * 32];
}
__device__ __forceinline__ float d_bil32(const float* fp, int W, int H, float gx, float gy) {
    float fx = (gx + 1.0f) * 0.5f * (float)(W - 1);
    float fy = (gy + 1.0f) * 0.5f * (float)(H - 1);
    float x0f = floorf(fx), y0f = floorf(fy);
    int x0 = (int)x0f, y0 = (int)y0f;
    float wx = fx - x0f, wy = fy - y0f;
    float v00 = d_samp32(fp, W, H, x0, y0);
    float v10 = d_samp32(fp, W, H, x0 + 1, y0);
    float v01 = d_samp32(fp, W, H, x0, y0 + 1);
    float v11 = d_samp32(fp, W, H, x0 + 1, y0 + 1);
    return v00 * (1.f - wx) * (1.f - wy) + v10 * wx * (1.f - wy) + v01 * (1.f - wx) * wy + v11 * wx * wy;
}

template <int TR>
__global__ __launch_bounds__(256) void k_deform(const float* __restrict__ offL, const float* __restrict__ awL,
                                                const float* __restrict__ ref,
                                                const float* __restrict__ f0, const float* __restrict__ f1,
                                                const float* __restrict__ f2, const float* __restrict__ f3,
                                                float* __restrict__ caf, float* __restrict__ attn_out,
                                                int Qn) {
    int row = blockIdx.x;  // b*Qn + q
    int b = row / Qn;
    int tid = threadIdx.x;
    __shared__ float attn_s[8][16];
    __shared__ float off_s[8][16][2];
    __shared__ float rxy[2];
    if (tid < 8) {
        int h = tid;
        const float* ap = awL + (size_t)row * 128 + h * 16;
        float mx = -INFINITY;
        float e[16];
#pragma unroll
        for (int j = 0; j < 16; j++) mx = fmaxf(mx, ap[j]);
        float ssum = 0.f;
#pragma unroll
        for (int j = 0; j < 16; j++) { e[j] = expf(ap[j] - mx); ssum += e[j]; }
        float inv = 1.0f / ssum;
        float* ao = attn_out + (size_t)row * 128 + h * 16;
#pragma unroll
        for (int j = 0; j < 16; j++) {
            float p = e[j] * inv;
            attn_s[h][j] = p;
            ao[j] = p;
        }
        const float* op = offL + (size_t)row * 256 + h * 32;
#pragma unroll
        for (int j = 0; j < 16; j++) {
            off_s[h][j][0] = tanhf(op[j * 2 + 0]);
            off_s[h][j][1] = tanhf(op[j * 2 + 1]);
        }
    }
    if (tid == 8) {
        rxy[0] = ref[(size_t)row * 2 + 0] * 2.f - 1.f;
        rxy[1] = ref[(size_t)row * 2 + 1] * 2.f - 1.f;
    }
    __syncthreads();
    int h = tid >> 5, c = tid & 31;
    float agg = 0.f;
#pragma unroll
    for (int l = 0; l < 4; l++) {
        const int H = 128 >> l;
        const float* base = (l == 0 ? f0 : l == 1 ? f1 : l == 2 ? f2 : f3);
        const float* fp;
        if (TR) fp = base + ((size_t)(b * 8 + h) * (H * H)) * 32 + c;
        else    fp = base + (size_t)(b * DD + h * 32 + c) * H * H;
#pragma unroll
        for (int p = 0; p < 4; p++) {
            int j = l * 4 + p;
            float sv;
            if (TR) sv = d_bil32(fp, H, H, rxy[0] + off_s[h][j][0], rxy[1] + off_s[h][j][1]);
            else    sv = d_bil(fp, H, H, rxy[0] + off_s[h][j][0], rxy[1] + off_s[h][j][1]);
            agg += attn_s[h][j] * sv;
        }
    }
    caf[(size_t)row * DD + h * 32 + c] = agg;
}

// ---------------- small per-row 2-output heads ----------------
__global__ __launch_bounds__(64) void k_refinit(const float* __restrict__ hbuf, const float* __restrict__ w2,
                                                const float* __restrict__ b2, float* __restrict__ ref) {
    int row = blockIdx.x, lane = threadIdx.x;
    const float* hp = hbuf + (size_t)row * DD;
    float s0 = 0.f, s1 = 0.f;
#pragma unroll
    for (int d = 0; d < 4; d++) {
        int dd = lane + d * 64;
        float v = hp[dd];
        s0 += v * w2[dd];
        s1 += v * w2[DD + dd];
    }
#pragma unroll
    for (int o = 32; o > 0; o >>= 1) { s0 += __shfl_down(s0, o); s1 += __shfl_down(s1, o); }
    if (lane == 0) {
        ref[(size_t)row * 2 + 0] = sigm(s0 + b2[0]);
        ref[(size_t)row * 2 + 1] = sigm(s1 + b2[1]);
    }
}

// refine + score fused (both read f_out row; chains identical to R0's k_refine / k_score).
__global__ __launch_bounds__(64) void k_refsc(const float* __restrict__ out, const float* __restrict__ rw,
                                              const float* __restrict__ rb, float* __restrict__ ref,
                                              const float* __restrict__ sw, const float* __restrict__ sb,
                                              float* __restrict__ score) {
    int row = blockIdx.x, lane = threadIdx.x;
    const float* op = out + (size_t)row * DD;
    float s0 = 0.f, s1 = 0.f;
#pragma unroll
    for (int d = 0; d < 4; d++) {
        int dd = lane + d * 64;
        float v = op[dd];
        s0 += v * rw[dd];
        s1 += v * rw[DD + dd];
    }
#pragma unroll
    for (int o = 32; o > 0; o >>= 1) { s0 += __shfl_down(s0, o); s1 += __shfl_down(s1, o); }
    if (lane == 0) {
        float r0 = ref[(size_t)row * 2 + 0] + tanhf(s0 + rb[0]) * 0.5f;
        float r1 = ref[(size_t)row * 2 + 1] + tanhf(s1 + rb[1]) * 0.5f;
        ref[(size_t)row * 2 + 0] = fminf(fmaxf(r0, 0.f), 1.f);
        ref[(size_t)row * 2 + 1] = fminf(fmaxf(r1, 0.f), 1.f);
        // score: exact sequential d-order dot
        float s = sb[0];
        for (int d = 0; d < DD; d++) s += op[d] * sw[d];
        score[row] = sigm(s);
    }
}

// ---------------- top-k (exact jax.lax.top_k: desc value, asc index on ties) ----------------
__global__ __launch_bounds__(256) void k_topk(const float* __restrict__ score, int* __restrict__ idx,
                                              int Qn, int PAD, int keep) {
    __shared__ u64 keys[1024];
    int b = blockIdx.x, tid = threadIdx.x;
    for (int q = tid; q < PAD; q += 256) {
        u64 key;
        if (q < Qn) {
            u32 u = __float_as_uint(score[b * Qn + q]);
            u = (u & 0x80000000u) ? ~u : (u | 0x80000000u);
            u32 hi = ~u;  // descending score, ascending index on ties
            key = (((u64)hi) << 32) | (u32)q;
        } else {
            key = 0xFFFFFFFFFFFFFFFFULL;
        }
        keys[q] = key;
    }
    __syncthreads();
    for (int k = 2; k <= PAD; k <<= 1) {
        for (int j = k >> 1; j > 0; j >>= 1) {
            for (int i = tid; i < PAD; i += 256) {
                int ij = i ^ j;
                if (ij > i) {
                    bool up = ((i & k) == 0);
                    u64 a = keys[i], c = keys[ij];
                    if ((a > c) == up) { keys[i] = c; keys[ij] = a; }
                }
            }
            __syncthreads();
        }
    }
    for (int t = tid; t < keep; t += 256) idx[b * keep + t] = (int)(keys[t] & 0xFFFFFFFFu);
}

__global__ __launch_bounds__(256) void k_gather(const float* __restrict__ osrc, const float* __restrict__ esrc,
                                                const float* __restrict__ rsrc, const int* __restrict__ idx,
                                                float* __restrict__ oT, float* __restrict__ eT,
                                                float* __restrict__ rT, int Qin, int keep) {
    int j = blockIdx.x;
    int b = j / keep;
    int src = idx[j];
    int tid = threadIdx.x;
    size_t srow = (size_t)(b * Qin + src), drow = (size_t)j;
    oT[drow * DD + tid] = osrc[srow * DD + tid];
    eT[drow * DD + tid] = esrc[srow * DD + tid];
    if (tid < 2) rT[drow * 2 + tid] = rsrc[srow * 2 + tid];
}

__global__ __launch_bounds__(256) void k_copyback(const float* __restrict__ oT, const float* __restrict__ eT,
                                                  const float* __restrict__ rT, float* __restrict__ o,
                                                  float* __restrict__ e, float* __restrict__ r) {
    int row = blockIdx.x, tid = threadIdx.x;
    o[(size_t)row * DD + tid] = oT[(size_t)row * DD + tid];
    e[(size_t)row * DD + tid] = eT[(size_t)row * DD + tid];
    if (tid < 2) r[(size_t)row * 2 + tid] = rT[(size_t)row * 2 + tid];
}

// =======================================================================================
extern "C" void kernel_launch(void* const* d_in, const int* in_sizes, int n_in,
                              void* d_out, int out_size, void* d_ws, size_t ws_size,
                              hipStream_t stream) {
    (void)in_sizes; (void)n_in; (void)out_size;
    const float* q_obj = (const float*)d_in[0];
    const float* q_emb = (const float*)d_in[1];
    const float* feat0 = (const float*)d_in[2];
    const float* feat1 = (const float*)d_in[3];
    const float* feat2 = (const float*)d_in[4];
    const float* feat3 = (const float*)d_in[5];
    const float* sa_in_w = (const float*)d_in[6];
    const float* sa_in_b = (const float*)d_in[7];
    const float* sa_out_w = (const float*)d_in[8];
    const float* sa_out_b = (const float*)d_in[9];
    const float* off_w = (const float*)d_in[10];
    const float* off_b = (const float*)d_in[11];
    const float* aw_w = (const float*)d_in[12];
    const float* aw_b = (const float*)d_in[13];
    const float* ca_out_w = (const float*)d_in[14];
    const float* ca_out_b = (const float*)d_in[15];
    const float* ff_w1 = (const float*)d_in[16];
    const float* ff_b1 = (const float*)d_in[17];
    const float* ff_w2 = (const float*)d_in[18];
    const float* ff_b2 = (const float*)d_in[19];
    const float* nsa_w = (const float*)d_in[20];
    const float* nsa_b = (const float*)d_in[21];
    const float* nca_w = (const float*)d_in[22];
    const float* nca_b = (const float*)d_in[23];
    const float* nff_w = (const float*)d_in[24];
    const float* nff_b = (const float*)d_in[25];
    const float* ref_w1 = (const float*)d_in[26];
    const float* ref_b1 = (const float*)d_in[27];
    const float* ref_w2 = (const float*)d_in[28];
    const float* ref_b2 = (const float*)d_in[29];
    const float* score_w = (const float*)d_in[30];
    const float* score_b = (const float*)d_in[31];
    const float* refine_w = (const float*)d_in[32];
    const float* refine_b = (const float*)d_in[33];

    float* outf = (float*)d_out;
    float* ws = (float*)d_ws;
    const int RD = 4000 * 256;  // 1,024,000 floats
    float* f_out = ws;
    float* f_emb = ws + RD;
    float* f_ln  = ws + 2 * RD;
    float* sc0   = ws + 3 * RD;  // FFN hidden spans sc0+sc1 (2*RD)
    float* sc1   = ws + 4 * RD;
    float* sc2   = ws + 5 * RD;
    float* f_ref = ws + 6 * RD;                      // 8000 floats
    float* f_sc  = ws + 6 * RD + 8000;               // 4000 floats (scores)
    int*   i_idx = (int*)(ws + 6 * RD + 12032);      // 2000 ints
    float* f_tr  = ws + 6 * RD + 16384;              // transposed feats: 22,282,240 floats
    static const s64 tr_ofs[4] = {0, 16777216, 20971520, 22020096};
    const size_t tr_need_bytes = ((size_t)(6 * RD + 16384) + 22282240ULL) * 4ULL;
    const bool use_tr = ws_size >= tr_need_bytes;

    static const int Qs[6] = {1000, 500, 250, 125, 62, 31};
    static const s64 out_ofs[6] = {0, 1024000, 1536000, 1792000, 1920000, 1983488};
    static const s64 attn_ofs[6] = {2015232, 2527232, 2783232, 2911232, 2975232, 3006976};

    hipMemcpyAsync(f_out, q_obj, (size_t)RD * 4, hipMemcpyDeviceToDevice, stream);
    hipMemcpyAsync(f_emb, q_emb, (size_t)RD * 4, hipMemcpyDeviceToDevice, stream);

    // one-time feature transpose to [b][h][spatial][c] (if workspace allows)
    if (use_tr) {
        k_trfeat<<<dim3(16384 / 64, 32), 256, 0, stream>>>(feat0, f_tr + tr_ofs[0], 16384);
        k_trfeat<<<dim3(4096 / 64, 32), 256, 0, stream>>>(feat1, f_tr + tr_ofs[1], 4096);
        k_trfeat<<<dim3(1024 / 64, 32), 256, 0, stream>>>(feat2, f_tr + tr_ofs[2], 1024);
        k_trfeat<<<dim3(256 / 64, 32), 256, 0, stream>>>(feat3, f_tr + tr_ofs[3], 256);
    }

    // initial reference points
    k_gemm<1, 0, 0><<<dim3(4, 63), 256, 0, stream>>>(f_emb, nullptr, ref_w1, ref_b1, nullptr, f_ln, 4000, 256, 256);
    k_refinit<<<4000, 64, 0, stream>>>(f_ln, ref_w2, ref_b2, f_ref);

    for (int i = 0; i < 6; i++) {
        const int Q = Qs[i];
        const int R = BB * Q;
        const int gy = (R + 63) / 64;
        const float* siw = sa_in_w + (size_t)i * 768 * 256;
        const float* sib = sa_in_b + (size_t)i * 768;

        // ---- self attention ----
        k_ln<<<R, 256, 0, stream>>>(f_out, nsa_w + i * 256, nsa_b + i * 256, f_ln);
        k_gemm_qkv<<<dim3(4, gy, 3), 256, 0, stream>>>(f_ln, f_emb, siw, sib, sc0, sc1, sc2, R, 256);
        k_mha<<<dim3((Q + 63) / 64, 32), 64, 0, stream>>>(sc0, sc1, sc2, f_ln, Q);
        k_gemm<0, 1, 0><<<dim3(4, gy), 256, 0, stream>>>(f_ln, nullptr, sa_out_w + (size_t)i * 65536,
                                                         sa_out_b + i * 256, f_out, f_out, R, 256, 256);

        // ---- deformable cross attention ----
        k_ln<<<R, 256, 0, stream>>>(f_out, nca_w + i * 256, nca_b + i * 256, f_ln);
        k_gemm_offaw<<<dim3(4, gy, 2), 256, 0, stream>>>(f_ln, f_emb, off_w + (size_t)i * 65536, off_b + i * 256,
                                                         aw_w + (size_t)i * 32768, aw_b + i * 128, sc0, sc1, R, 256);
        if (use_tr)
            k_deform<1><<<R, 256, 0, stream>>>(sc0, sc1, f_ref, f_tr + tr_ofs[0], f_tr + tr_ofs[1],
                                               f_tr + tr_ofs[2], f_tr + tr_ofs[3], sc2, outf + attn_ofs[i], Q);
        else
            k_deform<0><<<R, 256, 0, stream>>>(sc0, sc1, f_ref, feat0, feat1, feat2, feat3, sc2,
                                               outf + attn_ofs[i], Q);
        k_gemm<0, 1, 0><<<dim3(4, gy), 256, 0, stream>>>(sc2, nullptr, ca_out_w + (size_t)i * 65536,
                                                         ca_out_b + i * 256, f_out, f_out, R, 256, 256);

        // ---- FFN (hidden chunked: chunk<=2000 rows fits sc0..sc1); 2nd GEMM fuses layer store ----
        k_ln<<<R, 256, 0, stream>>>(f_out, nff_w + i * 256, nff_b + i * 256, f_ln);
        for (int r0 = 0; r0 < R; r0 += 2000) {
            int mc = R - r0; if (mc > 2000) mc = 2000;
            int gyc = (mc + 63) / 64;
            k_ff1<<<dim3(8, (mc + 127) / 128), 256, 0, stream>>>(f_ln + (size_t)r0 * 256,
                                                                 ff_w1 + (size_t)i * 262144, ff_b1 + i * 1024,
                                                                 sc0, mc);
            k_gemm_st2<<<dim3(4, gyc), 256, 0, stream>>>(sc0, ff_w2 + (size_t)i * 262144,
                                                         ff_b2 + i * 256, f_out + (size_t)r0 * 256,
                                                         f_out + (size_t)r0 * 256,
                                                         outf + out_ofs[i] + (size_t)r0 * 256, mc, 256, 1024);
        }

        // ---- refine ref points + scores, then top-k select + gather ----
        if (i < 5) {
            int keep = Qs[i + 1];
            int PAD = 1;
            while (PAD < Q) PAD <<= 1;
            k_refsc<<<R, 64, 0, stream>>>(f_out, refine_w, refine_b, f_ref, score_w, score_b, f_sc);
            k_topk<<<4, 256, 0, stream>>>(f_sc, i_idx, Q, PAD, keep);
            k_gather<<<4 * keep, 256, 0, stream>>>(f_out, f_emb, f_ref, i_idx, sc0, sc1, sc2, Q, keep);
            k_copyback<<<4 * keep, 256, 0, stream>>>(sc0, sc1, sc2, f_out, f_emb, f_ref);
        }
    }
}

// Round 5
// 2350.717 us; speedup vs baseline: 1.2754x; 1.2754x over previous
//
#include <hip/hip_runtime.h>
#include <hip/hip_bf16.h>

// Problem constants (static: B=4, Q0=1000, D=256, NH=8, HD=32, FF=1024, L=6, NL=4, NP=4)
// Inputs: fp32. Outputs: fp32.
// MHA/top-k NUMERICS CONTRACT: every per-query reduction chain (dot c-order, online-softmax
// j-order, GEMM k-order) must keep the exact sequential FP ordering — top-k set selection
// flips under ~1e-6 perturbations. R1 LESSON: redistributing the MHA DAG across lanes broke
// bits. Only load-source/load-width/scheduling changes with IDENTICAL expression text are safe.
// R4 LESSONS: (a) k_mha WITHOUT LDS staging re-streams K/V per wave (FETCH 2x, 373->604us) —
// LDS staging is strictly better; (b) 128^2-tile FFN1 starves the grid (128 blocks) — keep
// 64^2 tiles for these small-M GEMMs.
// R5: k_mha = R3 LDS structure + phase-split update (m-chain -> 8 independent expf -> l-chain
// -> acc sweeps with reg-prefetched V). Identical per-chain op order/text; only independent-op
// grouping changes, to overlap exp + LDS latencies under the 1-wave/SIMD occupancy floor.
#define BB 4
#define DD 256

typedef unsigned long long u64;
typedef long long s64;
typedef unsigned int u32;

__device__ __forceinline__ float sigm(float x) { return 1.0f / (1.0f + expf(-x)); }

// ---------------- LayerNorm (D=256, one row per block of 256 threads) ----------------
__global__ void k_ln(const float* __restrict__ x, const float* __restrict__ w,
                     const float* __restrict__ b, float* __restrict__ ln) {
    int row = blockIdx.x, tid = threadIdx.x;
    float v = x[(size_t)row * DD + tid];
    __shared__ float sred[4];
    float s = v;
#pragma unroll
    for (int o = 32; o > 0; o >>= 1) s += __shfl_down(s, o);
    if ((tid & 63) == 0) sred[tid >> 6] = s;
    __syncthreads();
    float mu = (sred[0] + sred[1] + sred[2] + sred[3]) * (1.0f / 256.0f);
    __syncthreads();
    float d = v - mu;
    float s2 = d * d;
#pragma unroll
    for (int o = 32; o > 0; o >>= 1) s2 += __shfl_down(s2, o);
    if ((tid & 63) == 0) sred[tid >> 6] = s2;
    __syncthreads();
    float var = (sred[0] + sred[1] + sred[2] + sred[3]) * (1.0f / 256.0f);
    float r = rsqrtf(var + 1e-5f);
    ln[(size_t)row * DD + tid] = d * r * w[tid] + b[tid];
}

// ---------------- GEMM core: C[M,N] = act((A+Pe)[M,K] @ W[N,K]^T + bias) (+ residual) ----------
// 64x64 tile, BK=16, 256 threads, 4x4 microtile, double-buffered LDS (1 barrier/iter).
// Per-output-element chain: strict ascending-k single-fma (acc += a*w) — bit-identical to R0.
template <int ACT, int RES>
__device__ __forceinline__ void gemm_core(float (*As)[16][64], float (*Ws)[16][64],
                                          const float* __restrict__ A, const float* __restrict__ Pe, int pe,
                                          const float* __restrict__ W, const float* __restrict__ bias,
                                          const float* __restrict__ Rm, float* __restrict__ C,
                                          float* __restrict__ C2,
                                          int M, int N, int K, int row0, int col0) {
    int tid = threadIdx.x;
    int tx = tid & 15, ty = tid >> 4;
    int lm = tid >> 2, lk = (tid & 3) * 4;
    float acc[4][4] = {{0.f}};
    int ar = row0 + lm;
    const float* Arow = A + (size_t)ar * K + lk;
    const float* Prow = pe ? (Pe + (size_t)ar * K + lk) : nullptr;
    const float* Wrow = W + (size_t)(col0 + lm) * K + lk;  // N multiple of 64
    float4 av = make_float4(0.f, 0.f, 0.f, 0.f), wv;
    if (ar < M) {
        av = *(const float4*)(Arow);
        if (pe) { float4 pv = *(const float4*)(Prow); av.x += pv.x; av.y += pv.y; av.z += pv.z; av.w += pv.w; }
    }
    wv = *(const float4*)(Wrow);
    As[0][lk + 0][lm] = av.x; As[0][lk + 1][lm] = av.y; As[0][lk + 2][lm] = av.z; As[0][lk + 3][lm] = av.w;
    Ws[0][lk + 0][lm] = wv.x; Ws[0][lk + 1][lm] = wv.y; Ws[0][lk + 2][lm] = wv.z; Ws[0][lk + 3][lm] = wv.w;
    __syncthreads();
    int nb = K >> 4;
    for (int t = 0; t < nb; t++) {
        int cur = t & 1, nxt = cur ^ 1;
        bool more = (t + 1 < nb);
        if (more) {
            int k0 = (t + 1) << 4;
            av = make_float4(0.f, 0.f, 0.f, 0.f);
            if (ar < M) {
                av = *(const float4*)(Arow + k0);
                if (pe) { float4 pv = *(const float4*)(Prow + k0); av.x += pv.x; av.y += pv.y; av.z += pv.z; av.w += pv.w; }
            }
            wv = *(const float4*)(Wrow + k0);
        }
#pragma unroll
        for (int kk = 0; kk < 16; kk++) {
            float4 a = *(const float4*)&As[cur][kk][ty << 2];
            float4 w = *(const float4*)&Ws[cur][kk][tx << 2];
            acc[0][0] += a.x * w.x; acc[0][1] += a.x * w.y; acc[0][2] += a.x * w.z; acc[0][3] += a.x * w.w;
            acc[1][0] += a.y * w.x; acc[1][1] += a.y * w.y; acc[1][2] += a.y * w.z; acc[1][3] += a.y * w.w;
            acc[2][0] += a.z * w.x; acc[2][1] += a.z * w.y; acc[2][2] += a.z * w.z; acc[2][3] += a.z * w.w;
            acc[3][0] += a.w * w.x; acc[3][1] += a.w * w.y; acc[3][2] += a.w * w.z; acc[3][3] += a.w * w.w;
        }
        if (more) {
            As[nxt][lk + 0][lm] = av.x; As[nxt][lk + 1][lm] = av.y; As[nxt][lk + 2][lm] = av.z; As[nxt][lk + 3][lm] = av.w;
            Ws[nxt][lk + 0][lm] = wv.x; Ws[nxt][lk + 1][lm] = wv.y; Ws[nxt][lk + 2][lm] = wv.z; Ws[nxt][lk + 3][lm] = wv.w;
        }
        __syncthreads();
    }
#pragma unroll
    for (int i2 = 0; i2 < 4; i2++) {
        int r = row0 + (ty << 2) + i2;
        if (r >= M) continue;
        int cc = col0 + (tx << 2);
        float4 v;
        v.x = acc[i2][0] + bias[cc + 0];
        v.y = acc[i2][1] + bias[cc + 1];
        v.z = acc[i2][2] + bias[cc + 2];
        v.w = acc[i2][3] + bias[cc + 3];
        if (ACT == 1) { v.x = fmaxf(v.x, 0.f); v.y = fmaxf(v.y, 0.f); v.z = fmaxf(v.z, 0.f); v.w = fmaxf(v.w, 0.f); }
        if (RES == 1) {
            float4 rm = *(const float4*)(Rm + (size_t)r * N + cc);
            v.x += rm.x; v.y += rm.y; v.z += rm.z; v.w += rm.w;
        }
        *(float4*)(C + (size_t)r * N + cc) = v;
        if (C2) *(float4*)(C2 + (size_t)r * N + cc) = v;
    }
}

template <int ACT, int RES, int PE>
__global__ __launch_bounds__(256) void k_gemm(const float* __restrict__ A, const float* __restrict__ Pe,
                                              const float* __restrict__ W, const float* __restrict__ bias,
                                              const float* __restrict__ Rm, float* __restrict__ C,
                                              int M, int N, int K) {
    __shared__ float As[2][16][64];
    __shared__ float Ws[2][16][64];
    gemm_core<ACT, RES>(As, Ws, A, Pe, PE, W, bias, Rm, C, nullptr, M, N, K, blockIdx.y * 64, blockIdx.x * 64);
}

// FFN second GEMM with fused layer-output store (C2 = outf region; same values as C).
__global__ __launch_bounds__(256) void k_gemm_st2(const float* __restrict__ A, const float* __restrict__ W,
                                                  const float* __restrict__ bias, const float* __restrict__ Rm,
                                                  float* __restrict__ C, float* __restrict__ C2,
                                                  int M, int N, int K) {
    __shared__ float As[2][16][64];
    __shared__ float Ws[2][16][64];
    gemm_core<0, 1>(As, Ws, A, nullptr, 0, W, bias, Rm, C, C2, M, N, K, blockIdx.y * 64, blockIdx.x * 64);
}

// QKV merged: blockIdx.z in {0,1,2} picks weight block / bias / output; z<2 adds Pe.
__global__ __launch_bounds__(256) void k_gemm_qkv(const float* __restrict__ A, const float* __restrict__ Pe,
                                                  const float* __restrict__ Wqkv, const float* __restrict__ bqkv,
                                                  float* __restrict__ Cq, float* __restrict__ Ck, float* __restrict__ Cv,
                                                  int M, int K) {
    __shared__ float As[2][16][64];
    __shared__ float Ws[2][16][64];
    int z = blockIdx.z;
    const float* W = Wqkv + (size_t)z * 256 * K;
    const float* bias = bqkv + z * 256;
    float* C = (z == 0) ? Cq : (z == 1) ? Ck : Cv;
    gemm_core<0, 0>(As, Ws, A, Pe, (z < 2) ? 1 : 0, W, bias, nullptr, C, nullptr, M, 256, K,
                    blockIdx.y * 64, blockIdx.x * 64);
}

// off (N=256) + aw (N=128) merged: z picks; z=1 blocks with col0>=128 exit whole-block.
__global__ __launch_bounds__(256) void k_gemm_offaw(const float* __restrict__ A, const float* __restrict__ Pe,
                                                    const float* __restrict__ Woff, const float* __restrict__ boff,
                                                    const float* __restrict__ Waw, const float* __restrict__ baw,
                                                    float* __restrict__ Coff, float* __restrict__ Caw,
                                                    int M, int K) {
    __shared__ float As[2][16][64];
    __shared__ float Ws[2][16][64];
    int z = blockIdx.z;
    int N = (z == 0) ? 256 : 128;
    if ((int)(blockIdx.x * 64) >= N) return;  // uniform whole-block exit (before any barrier)
    gemm_core<0, 0>(As, Ws, A, Pe, 1, (z == 0) ? Woff : Waw, (z == 0) ? boff : baw, nullptr,
                    (z == 0) ? Coff : Caw, nullptr, M, N, K, blockIdx.y * 64, blockIdx.x * 64);
}

// ---------------- MHA: sequential-key flash attention, HD=32, 1 query/thread ----------------
// R3 LDS structure (passed, 373us) + R5 phase-split: per 8-key group,
//   A) m-chain: 8 serial fmax (cheap);
//   B) 8 INDEPENDENT expf (latencies overlap) + serial l-chain;
//   C) 8 acc sweeps with sc/p in regs and V prefetched one key ahead into regs.
// Every chain (m, l, each acc[c]) keeps exact u-order and the same expression text as R3;
// only the grouping of mutually-independent ops changes. Dot block pipelined one group ahead.
#define MHA_DOT8(SREG, JJ)                                                       \
    {                                                                            \
        _Pragma("unroll")                                                        \
        for (int u = 0; u < 8; u++) SREG[u] = 0.f;                               \
        _Pragma("unroll")                                                        \
        for (int c4 = 0; c4 < 8; c4++) {                                         \
            float q0 = qv[c4 * 4 + 0], q1 = qv[c4 * 4 + 1];                      \
            float q2 = qv[c4 * 4 + 2], q3 = qv[c4 * 4 + 3];                      \
            _Pragma("unroll")                                                    \
            for (int u = 0; u < 8; u++) {                                        \
                float4 k4 = *(const float4*)&Ks[(JJ) + u][c4 * 4];               \
                SREG[u] += q0 * k4.x; SREG[u] += q1 * k4.y;                      \
                SREG[u] += q2 * k4.z; SREG[u] += q3 * k4.w;                      \
            }                                                                    \
        }                                                                        \
    }

__global__ __launch_bounds__(64) void k_mha(const float* __restrict__ Qb, const float* __restrict__ Kb,
                                            const float* __restrict__ Vb, float* __restrict__ Ob, int Qn) {
    int bh = blockIdx.y;
    int b = bh >> 3, h = bh & 7;
    int lane = threadIdx.x;
    int qi = blockIdx.x * 64 + lane;
    __shared__ float Ks[64][36];  // +4 pad: conflict-free; float4 columns stay 16B-aligned
    __shared__ float Vs[64][36];
    float qv[32];
    float acc[32];
#pragma unroll
    for (int c = 0; c < 32; c++) acc[c] = 0.f;
    float m = -INFINITY, l = 0.f;
    const float scale = 0.17677669529663687f;  // 1/sqrt(32)
    bool active = qi < Qn;
    if (active) {
        const float4* qp = (const float4*)(Qb + ((size_t)(b * Qn + qi)) * DD + h * 32);
#pragma unroll
        for (int c4 = 0; c4 < 8; c4++) {
            float4 t = qp[c4];
            qv[c4 * 4 + 0] = t.x * scale; qv[c4 * 4 + 1] = t.y * scale;
            qv[c4 * 4 + 2] = t.z * scale; qv[c4 * 4 + 3] = t.w * scale;
        }
    } else {
#pragma unroll
        for (int c = 0; c < 32; c++) qv[c] = 0.f;
    }
    for (int k0 = 0; k0 < Qn; k0 += 64) {
        int nk = Qn - k0; if (nk > 64) nk = 64;
        if (lane < nk) {
            const float4* kp = (const float4*)(Kb + ((size_t)(b * Qn + k0 + lane)) * DD + h * 32);
            const float4* vp = (const float4*)(Vb + ((size_t)(b * Qn + k0 + lane)) * DD + h * 32);
#pragma unroll
            for (int c4 = 0; c4 < 8; c4++) {
                *(float4*)&Ks[lane][c4 * 4] = kp[c4];
                *(float4*)&Vs[lane][c4 * 4] = vp[c4];
            }
        }
        __syncthreads();
        int ng = nk >> 3;
        float scur[8], snxt[8];
        if (ng > 0) MHA_DOT8(scur, 0)
        for (int g = 0; g < ng; g++) {
            int jj = g << 3;
            bool morep = (g + 1 < ng);
            if (morep) MHA_DOT8(snxt, jj + 8)
            // --- phase A: m-chain (same fmax ops, same order as R3) ---
            float mch[9];
            mch[0] = m;
#pragma unroll
            for (int u = 0; u < 8; u++) mch[u + 1] = fmaxf(mch[u], scur[u]);
            // --- phase B: 8 independent expf (same expression per key), then serial l-chain ---
            float e8[8];
#pragma unroll
            for (int u = 0; u < 8; u++) e8[u] = expf(fminf(mch[u] - scur[u], scur[u] - mch[u]));
            float sc8[8], p8[8];
#pragma unroll
            for (int u = 0; u < 8; u++) {
                bool gt = scur[u] > mch[u];
                sc8[u] = gt ? e8[u] : 1.0f;
                p8[u] = gt ? 1.0f : e8[u];
                l = l * sc8[u] + p8[u];
            }
            m = mch[8];
            // --- phase C: acc sweeps in exact u order; V one-key register prefetch ---
            float4 vc[8], vn[8];
#pragma unroll
            for (int c4 = 0; c4 < 8; c4++) vc[c4] = *(const float4*)&Vs[jj][c4 * 4];
#pragma unroll
            for (int u = 0; u < 8; u++) {
                if (u < 7) {
#pragma unroll
                    for (int c4 = 0; c4 < 8; c4++) vn[c4] = *(const float4*)&Vs[jj + u + 1][c4 * 4];
                }
                float sc = sc8[u], p = p8[u];
#pragma unroll
                for (int c4 = 0; c4 < 8; c4++) {
                    acc[c4 * 4 + 0] = acc[c4 * 4 + 0] * sc + p * vc[c4].x;
                    acc[c4 * 4 + 1] = acc[c4 * 4 + 1] * sc + p * vc[c4].y;
                    acc[c4 * 4 + 2] = acc[c4 * 4 + 2] * sc + p * vc[c4].z;
                    acc[c4 * 4 + 3] = acc[c4 * 4 + 3] * sc + p * vc[c4].w;
                }
                if (u < 7) {
#pragma unroll
                    for (int c4 = 0; c4 < 8; c4++) vc[c4] = vn[c4];
                }
            }
            if (morep) {
#pragma unroll
                for (int u = 0; u < 8; u++) scur[u] = snxt[u];
            }
        }
        for (int j = ng << 3; j < nk; j++) {
            float sv = 0.f;
#pragma unroll
            for (int c4 = 0; c4 < 8; c4++) {
                float4 k4 = *(const float4*)&Ks[j][c4 * 4];
                sv += qv[c4 * 4 + 0] * k4.x; sv += qv[c4 * 4 + 1] * k4.y;
                sv += qv[c4 * 4 + 2] * k4.z; sv += qv[c4 * 4 + 3] * k4.w;
            }
            float mn = fmaxf(m, sv);
            float e = expf(fminf(m - sv, sv - m));
            bool gt = sv > m;
            float sc = gt ? e : 1.0f;
            float p = gt ? 1.0f : e;
            l = l * sc + p;
            m = mn;
#pragma unroll
            for (int c4 = 0; c4 < 8; c4++) {
                float4 v4 = *(const float4*)&Vs[j][c4 * 4];
                acc[c4 * 4 + 0] = acc[c4 * 4 + 0] * sc + p * v4.x;
                acc[c4 * 4 + 1] = acc[c4 * 4 + 1] * sc + p * v4.y;
                acc[c4 * 4 + 2] = acc[c4 * 4 + 2] * sc + p * v4.z;
                acc[c4 * 4 + 3] = acc[c4 * 4 + 3] * sc + p * v4.w;
            }
        }
        __syncthreads();
    }
    if (active) {
        float inv = 1.0f / l;
        float* op = Ob + ((size_t)(b * Qn + qi)) * DD + h * 32;
#pragma unroll
        for (int c4 = 0; c4 < 8; c4++) {
            float4 o;
            o.x = acc[c4 * 4 + 0] * inv; o.y = acc[c4 * 4 + 1] * inv;
            o.z = acc[c4 * 4 + 2] * inv; o.w = acc[c4 * 4 + 3] * inv;
            *(float4*)(op + c4 * 4) = o;
        }
    }
}

// ---------------- feature transpose: [b][c=256][H][W] -> [b][h][H*W][hd=32] ----------------
// Pure data movement (bit-exact). Coalesced reads (64-float runs) and writes (128B runs).
__global__ __launch_bounds__(256) void k_trfeat(const float* __restrict__ in, float* __restrict__ out, int HH) {
    __shared__ float t[32][65];
    int bh = blockIdx.y;             // b*8 + h
    int b = bh >> 3, h = bh & 7;
    int s0 = blockIdx.x * 64;
    int tid = threadIdx.x;
    const float* ip = in + ((size_t)(b * 256 + h * 32)) * HH + s0;
#pragma unroll
    for (int i = 0; i < 8; i++) {
        int idx = i * 256 + tid;
        int c = idx >> 6, s = idx & 63;
        t[c][s] = ip[(size_t)c * HH + s];
    }
    __syncthreads();
    float* op = out + ((size_t)bh * HH + s0) * 32;
#pragma unroll
    for (int i = 0; i < 8; i++) {
        int idx = i * 256 + tid;
        int s = idx >> 5, c = idx & 31;
        op[(size_t)s * 32 + c] = t[c][s];
    }
}

// ---------------- deformable sampling ----------------
__device__ __forceinline__ float d_samp(const float* fp, int W, int H, int x, int y) {
    if (x < 0 || x > W - 1 || y < 0 || y > H - 1) return 0.f;
    return fp[y * W + x];
}
__device__ __forceinline__ float d_bil(const float* fp, int W, int H, float gx, float gy) {
    float fx = (gx + 1.0f) * 0.5f * (float)(W - 1);
    float fy = (gy + 1.0f) * 0.5f * (float)(H - 1);
    float x0f = floorf(fx), y0f = floorf(fy);
    int x0 = (int)x0f, y0 = (int)y0f;
    float wx = fx - x0f, wy = fy - y0f;
    float v00 = d_samp(fp, W, H, x0, y0);
    float v10 = d_samp(fp, W, H, x0 + 1, y0);
    float v01 = d_samp(fp, W, H, x0, y0 + 1);
    float v11 = d_samp(fp, W, H, x0 + 1, y0 + 1);
    return v00 * (1.f - wx) * (1.f - wy) + v10 * wx * (1.f - wy) + v01 * (1.f - wx) * wy + v11 * wx * wy;
}
// stride-32 (transposed-layout) variants: identical arithmetic, only addressing differs.
__device__ __forceinline__ float d_samp32(const float* fp, int W, int H, int x, int y) {
    if (x < 0 || x > W - 1 || y < 0 || y > H - 1) return 0.f;
    return fp[(size_t)(y * W + x) * 32];
}
__device__ __forceinline__ float d_bil32(const float* fp, int W, int H, float gx, float gy) {
    float fx = (gx + 1.0f) * 0.5f * (float)(W - 1);
    float fy = (gy + 1.0f) * 0.5f * (float)(H - 1);
    float x0f = floorf(fx), y0f = floorf(fy);
    int x0 = (int)x0f, y0 = (int)y0f;
    float wx = fx - x0f, wy = fy - y0f;
    float v00 = d_samp32(fp, W, H, x0, y0);
    float v10 = d_samp32(fp, W, H, x0 + 1, y0);
    float v01 = d_samp32(fp, W, H, x0, y0 + 1);
    float v11 = d_samp32(fp, W, H, x0 + 1, y0 + 1);
    return v00 * (1.f - wx) * (1.f - wy) + v10 * wx * (1.f - wy) + v01 * (1.f - wx) * wy + v11 * wx * wy;
}

template <int TR>
__global__ __launch_bounds__(256) void k_deform(const float* __restrict__ offL, const float* __restrict__ awL,
                                                const float* __restrict__ ref,
                                                const float* __restrict__ f0, const float* __restrict__ f1,
                                                const float* __restrict__ f2, const float* __restrict__ f3,
                                                float* __restrict__ caf, float* __restrict__ attn_out,
                                                int Qn) {
    int row = blockIdx.x;  // b*Qn + q
    int b = row / Qn;
    int tid = threadIdx.x;
    __shared__ float attn_s[8][16];
    __shared__ float off_s[8][16][2];
    __shared__ float rxy[2];
    if (tid < 8) {
        int h = tid;
        const float* ap = awL + (size_t)row * 128 + h * 16;
        float mx = -INFINITY;
        float e[16];
#pragma unroll
        for (int j = 0; j < 16; j++) mx = fmaxf(mx, ap[j]);
        float ssum = 0.f;
#pragma unroll
        for (int j = 0; j < 16; j++) { e[j] = expf(ap[j] - mx); ssum += e[j]; }
        float inv = 1.0f / ssum;
        float* ao = attn_out + (size_t)row * 128 + h * 16;
#pragma unroll
        for (int j = 0; j < 16; j++) {
            float p = e[j] * inv;
            attn_s[h][j] = p;
            ao[j] = p;
        }
        const float* op = offL + (size_t)row * 256 + h * 32;
#pragma unroll
        for (int j = 0; j < 16; j++) {
            off_s[h][j][0] = tanhf(op[j * 2 + 0]);
            off_s[h][j][1] = tanhf(op[j * 2 + 1]);
        }
    }
    if (tid == 8) {
        rxy[0] = ref[(size_t)row * 2 + 0] * 2.f - 1.f;
        rxy[1] = ref[(size_t)row * 2 + 1] * 2.f - 1.f;
    }
    __syncthreads();
    int h = tid >> 5, c = tid & 31;
    float agg = 0.f;
#pragma unroll
    for (int l = 0; l < 4; l++) {
        const int H = 128 >> l;
        const float* base = (l == 0 ? f0 : l == 1 ? f1 : l == 2 ? f2 : f3);
        const float* fp;
        if (TR) fp = base + ((size_t)(b * 8 + h) * (H * H)) * 32 + c;
        else    fp = base + (size_t)(b * DD + h * 32 + c) * H * H;
#pragma unroll
        for (int p = 0; p < 4; p++) {
            int j = l * 4 + p;
            float sv;
            if (TR) sv = d_bil32(fp, H, H, rxy[0] + off_s[h][j][0], rxy[1] + off_s[h][j][1]);
            else    sv = d_bil(fp, H, H, rxy[0] + off_s[h][j][0], rxy[1] + off_s[h][j][1]);
            agg += attn_s[h][j] * sv;
        }
    }
    caf[(size_t)row * DD + h * 32 + c] = agg;
}

// ---------------- small per-row 2-output heads ----------------
__global__ __launch_bounds__(64) void k_refinit(const float* __restrict__ hbuf, const float* __restrict__ w2,
                                                const float* __restrict__ b2, float* __restrict__ ref) {
    int row = blockIdx.x, lane = threadIdx.x;
    const float* hp = hbuf + (size_t)row * DD;
    float s0 = 0.f, s1 = 0.f;
#pragma unroll
    for (int d = 0; d < 4; d++) {
        int dd = lane + d * 64;
        float v = hp[dd];
        s0 += v * w2[dd];
        s1 += v * w2[DD + dd];
    }
#pragma unroll
    for (int o = 32; o > 0; o >>= 1) { s0 += __shfl_down(s0, o); s1 += __shfl_down(s1, o); }
    if (lane == 0) {
        ref[(size_t)row * 2 + 0] = sigm(s0 + b2[0]);
        ref[(size_t)row * 2 + 1] = sigm(s1 + b2[1]);
    }
}

// refine + score fused (both read f_out row; chains identical to R0's k_refine / k_score).
__global__ __launch_bounds__(64) void k_refsc(const float* __restrict__ out, const float* __restrict__ rw,
                                              const float* __restrict__ rb, float* __restrict__ ref,
                                              const float* __restrict__ sw, const float* __restrict__ sb,
                                              float* __restrict__ score) {
    int row = blockIdx.x, lane = threadIdx.x;
    const float* op = out + (size_t)row * DD;
    float s0 = 0.f, s1 = 0.f;
#pragma unroll
    for (int d = 0; d < 4; d++) {
        int dd = lane + d * 64;
        float v = op[dd];
        s0 += v * rw[dd];
        s1 += v * rw[DD + dd];
    }
#pragma unroll
    for (int o = 32; o > 0; o >>= 1) { s0 += __shfl_down(s0, o); s1 += __shfl_down(s1, o); }
    if (lane == 0) {
        float r0 = ref[(size_t)row * 2 + 0] + tanhf(s0 + rb[0]) * 0.5f;
        float r1 = ref[(size_t)row * 2 + 1] + tanhf(s1 + rb[1]) * 0.5f;
        ref[(size_t)row * 2 + 0] = fminf(fmaxf(r0, 0.f), 1.f);
        ref[(size_t)row * 2 + 1] = fminf(fmaxf(r1, 0.f), 1.f);
        // score: exact sequential d-order dot
        float s = sb[0];
        for (int d = 0; d < DD; d++) s += op[d] * sw[d];
        score[row] = sigm(s);
    }
}

// ---------------- top-k (exact jax.lax.top_k: desc value, asc index on ties) ----------------
__global__ __launch_bounds__(256) void k_topk(const float* __restrict__ score, int* __restrict__ idx,
                                              int Qn, int PAD, int keep) {
    __shared__ u64 keys[1024];
    int b = blockIdx.x, tid = threadIdx.x;
    for (int q = tid; q < PAD; q += 256) {
        u64 key;
        if (q < Qn) {
            u32 u = __float_as_uint(score[b * Qn + q]);
            u = (u & 0x80000000u) ? ~u : (u | 0x80000000u);
            u32 hi = ~u;  // descending score, ascending index on ties
            key = (((u64)hi) << 32) | (u32)q;
        } else {
            key = 0xFFFFFFFFFFFFFFFFULL;
        }
        keys[q] = key;
    }
    __syncthreads();
    for (int k = 2; k <= PAD; k <<= 1) {
        for (int j = k >> 1; j > 0; j >>= 1) {
            for (int i = tid; i < PAD; i += 256) {
                int ij = i ^ j;
                if (ij > i) {
                    bool up = ((i & k) == 0);
                    u64 a = keys[i], c = keys[ij];
                    if ((a > c) == up) { keys[i] = c; keys[ij] = a; }
                }
            }
            __syncthreads();
        }
    }
    for (int t = tid; t < keep; t += 256) idx[b * keep + t] = (int)(keys[t] & 0xFFFFFFFFu);
}

__global__ __launch_bounds__(256) void k_gather(const float* __restrict__ osrc, const float* __restrict__ esrc,
                                                const float* __restrict__ rsrc, const int* __restrict__ idx,
                                                float* __restrict__ oT, float* __restrict__ eT,
                                                float* __restrict__ rT, int Qin, int keep) {
    int j = blockIdx.x;
    int b = j / keep;
    int src = idx[j];
    int tid = threadIdx.x;
    size_t srow = (size_t)(b * Qin + src), drow = (size_t)j;
    oT[drow * DD + tid] = osrc[srow * DD + tid];
    eT[drow * DD + tid] = esrc[srow * DD + tid];
    if (tid < 2) rT[drow * 2 + tid] = rsrc[srow * 2 + tid];
}

__global__ __launch_bounds__(256) void k_copyback(const float* __restrict__ oT, const float* __restrict__ eT,
                                                  const float* __restrict__ rT, float* __restrict__ o,
                                                  float* __restrict__ e, float* __restrict__ r) {
    int row = blockIdx.x, tid = threadIdx.x;
    o[(size_t)row * DD + tid] = oT[(size_t)row * DD + tid];
    e[(size_t)row * DD + tid] = eT[(size_t)row * DD + tid];
    if (tid < 2) r[(size_t)row * 2 + tid] = rT[(size_t)row * 2 + tid];
}

// =======================================================================================
extern "C" void kernel_launch(void* const* d_in, const int* in_sizes, int n_in,
                              void* d_out, int out_size, void* d_ws, size_t ws_size,
                              hipStream_t stream) {
    (void)in_sizes; (void)n_in; (void)out_size;
    const float* q_obj = (const float*)d_in[0];
    const float* q_emb = (const float*)d_in[1];
    const float* feat0 = (const float*)d_in[2];
    const float* feat1 = (const float*)d_in[3];
    const float* feat2 = (const float*)d_in[4];
    const float* feat3 = (const float*)d_in[5];
    const float* sa_in_w = (const float*)d_in[6];
    const float* sa_in_b = (const float*)d_in[7];
    const float* sa_out_w = (const float*)d_in[8];
    const float* sa_out_b = (const float*)d_in[9];
    const float* off_w = (const float*)d_in[10];
    const float* off_b = (const float*)d_in[11];
    const float* aw_w = (const float*)d_in[12];
    const float* aw_b = (const float*)d_in[13];
    const float* ca_out_w = (const float*)d_in[14];
    const float* ca_out_b = (const float*)d_in[15];
    const float* ff_w1 = (const float*)d_in[16];
    const float* ff_b1 = (const float*)d_in[17];
    const float* ff_w2 = (const float*)d_in[18];
    const float* ff_b2 = (const float*)d_in[19];
    const float* nsa_w = (const float*)d_in[20];
    const float* nsa_b = (const float*)d_in[21];
    const float* nca_w = (const float*)d_in[22];
    const float* nca_b = (const float*)d_in[23];
    const float* nff_w = (const float*)d_in[24];
    const float* nff_b = (const float*)d_in[25];
    const float* ref_w1 = (const float*)d_in[26];
    const float* ref_b1 = (const float*)d_in[27];
    const float* ref_w2 = (const float*)d_in[28];
    const float* ref_b2 = (const float*)d_in[29];
    const float* score_w = (const float*)d_in[30];
    const float* score_b = (const float*)d_in[31];
    const float* refine_w = (const float*)d_in[32];
    const float* refine_b = (const float*)d_in[33];

    float* outf = (float*)d_out;
    float* ws = (float*)d_ws;
    const int RD = 4000 * 256;  // 1,024,000 floats
    float* f_out = ws;
    float* f_emb = ws + RD;
    float* f_ln  = ws + 2 * RD;
    float* sc0   = ws + 3 * RD;  // FFN hidden spans sc0+sc1 (2*RD)
    float* sc1   = ws + 4 * RD;
    float* sc2   = ws + 5 * RD;
    float* f_ref = ws + 6 * RD;                      // 8000 floats
    float* f_sc  = ws + 6 * RD + 8000;               // 4000 floats (scores)
    int*   i_idx = (int*)(ws + 6 * RD + 12032);      // 2000 ints
    float* f_tr  = ws + 6 * RD + 16384;              // transposed feats: 22,282,240 floats
    static const s64 tr_ofs[4] = {0, 16777216, 20971520, 22020096};
    const size_t tr_need_bytes = ((size_t)(6 * RD + 16384) + 22282240ULL) * 4ULL;
    const bool use_tr = ws_size >= tr_need_bytes;

    static const int Qs[6] = {1000, 500, 250, 125, 62, 31};
    static const s64 out_ofs[6] = {0, 1024000, 1536000, 1792000, 1920000, 1983488};
    static const s64 attn_ofs[6] = {2015232, 2527232, 2783232, 2911232, 2975232, 3006976};

    hipMemcpyAsync(f_out, q_obj, (size_t)RD * 4, hipMemcpyDeviceToDevice, stream);
    hipMemcpyAsync(f_emb, q_emb, (size_t)RD * 4, hipMemcpyDeviceToDevice, stream);

    // one-time feature transpose to [b][h][spatial][c] (if workspace allows)
    if (use_tr) {
        k_trfeat<<<dim3(16384 / 64, 32), 256, 0, stream>>>(feat0, f_tr + tr_ofs[0], 16384);
        k_trfeat<<<dim3(4096 / 64, 32), 256, 0, stream>>>(feat1, f_tr + tr_ofs[1], 4096);
        k_trfeat<<<dim3(1024 / 64, 32), 256, 0, stream>>>(feat2, f_tr + tr_ofs[2], 1024);
        k_trfeat<<<dim3(256 / 64, 32), 256, 0, stream>>>(feat3, f_tr + tr_ofs[3], 256);
    }

    // initial reference points
    k_gemm<1, 0, 0><<<dim3(4, 63), 256, 0, stream>>>(f_emb, nullptr, ref_w1, ref_b1, nullptr, f_ln, 4000, 256, 256);
    k_refinit<<<4000, 64, 0, stream>>>(f_ln, ref_w2, ref_b2, f_ref);

    for (int i = 0; i < 6; i++) {
        const int Q = Qs[i];
        const int R = BB * Q;
        const int gy = (R + 63) / 64;
        const float* siw = sa_in_w + (size_t)i * 768 * 256;
        const float* sib = sa_in_b + (size_t)i * 768;

        // ---- self attention ----
        k_ln<<<R, 256, 0, stream>>>(f_out, nsa_w + i * 256, nsa_b + i * 256, f_ln);
        k_gemm_qkv<<<dim3(4, gy, 3), 256, 0, stream>>>(f_ln, f_emb, siw, sib, sc0, sc1, sc2, R, 256);
        k_mha<<<dim3((Q + 63) / 64, 32), 64, 0, stream>>>(sc0, sc1, sc2, f_ln, Q);
        k_gemm<0, 1, 0><<<dim3(4, gy), 256, 0, stream>>>(f_ln, nullptr, sa_out_w + (size_t)i * 65536,
                                                         sa_out_b + i * 256, f_out, f_out, R, 256, 256);

        // ---- deformable cross attention ----
        k_ln<<<R, 256, 0, stream>>>(f_out, nca_w + i * 256, nca_b + i * 256, f_ln);
        k_gemm_offaw<<<dim3(4, gy, 2), 256, 0, stream>>>(f_ln, f_emb, off_w + (size_t)i * 65536, off_b + i * 256,
                                                         aw_w + (size_t)i * 32768, aw_b + i * 128, sc0, sc1, R, 256);
        if (use_tr)
            k_deform<1><<<R, 256, 0, stream>>>(sc0, sc1, f_ref, f_tr + tr_ofs[0], f_tr + tr_ofs[1],
                                               f_tr + tr_ofs[2], f_tr + tr_ofs[3], sc2, outf + attn_ofs[i], Q);
        else
            k_deform<0><<<R, 256, 0, stream>>>(sc0, sc1, f_ref, feat0, feat1, feat2, feat3, sc2,
                                               outf + attn_ofs[i], Q);
        k_gemm<0, 1, 0><<<dim3(4, gy), 256, 0, stream>>>(sc2, nullptr, ca_out_w + (size_t)i * 65536,
                                                         ca_out_b + i * 256, f_out, f_out, R, 256, 256);

        // ---- FFN (hidden chunked: chunk<=2000 rows fits sc0..sc1); 2nd GEMM fuses layer store ----
        k_ln<<<R, 256, 0, stream>>>(f_out, nff_w + i * 256, nff_b + i * 256, f_ln);
        for (int r0 = 0; r0 < R; r0 += 2000) {
            int mc = R - r0; if (mc > 2000) mc = 2000;
            int gyc = (mc + 63) / 64;
            k_gemm<1, 0, 0><<<dim3(16, gyc), 256, 0, stream>>>(f_ln + (size_t)r0 * 256, nullptr,
                                                               ff_w1 + (size_t)i * 262144, ff_b1 + i * 1024,
                                                               nullptr, sc0, mc, 1024, 256);
            k_gemm_st2<<<dim3(4, gyc), 256, 0, stream>>>(sc0, ff_w2 + (size_t)i * 262144,
                                                         ff_b2 + i * 256, f_out + (size_t)r0 * 256,
                                                         f_out + (size_t)r0 * 256,
                                                         outf + out_ofs[i] + (size_t)r0 * 256, mc, 256, 1024);
        }

        // ---- refine ref points + scores, then top-k select + gather ----
        if (i < 5) {
            int keep = Qs[i + 1];
            int PAD = 1;
            while (PAD < Q) PAD <<= 1;
            k_refsc<<<R, 64, 0, stream>>>(f_out, refine_w, refine_b, f_ref, score_w, score_b, f_sc);
            k_topk<<<4, 256, 0, stream>>>(f_sc, i_idx, Q, PAD, keep);
            k_gather<<<4 * keep, 256, 0, stream>>>(f_out, f_emb, f_ref, i_idx, sc0, sc1, sc2, Q, keep);
            k_copyback<<<4 * keep, 256, 0, stream>>>(sc0, sc1, sc2, f_out, f_emb, f_ref);
        }
    }
}

// Round 6
// 2117.402 us; speedup vs baseline: 1.4159x; 1.1102x over previous
//
#include <hip/hip_runtime.h>
#include <hip/hip_bf16.h>

// Problem constants (static: B=4, Q0=1000, D=256, NH=8, HD=32, FF=1024, L=6, NL=4, NP=4)
// Inputs: fp32. Outputs: fp32.
// MHA/top-k NUMERICS CONTRACT: every per-query reduction chain (dot c-order, online-softmax
// j-order, GEMM k-order) must keep the exact sequential FP ordering — top-k set selection
// flips under ~1e-6 perturbations. R1 LESSON: redistributing one chain ACROSS lanes broke
// bits. Chains may move between threads only if each chain stays WHOLE within one thread
// with identical expression text.
// R4 LESSONS: no-LDS K/V streaming doubles FETCH (slower); 128^2 FFN tile starves the grid.
// R5 LESSON: wave-side scheduling (phase-split, prefetch) is exhausted at ~369us — the wall
// is 0.5 waves/SIMD occupancy, structurally capped by 1 thread per (query,head).
// R6: split k_mha: (1) k_qk precomputes ALL scores in a machine-filling parallel kernel —
// each score is an independent whole-thread chain with byte-identical MHA_DOT8 text;
// (2) k_mha_s runs the serial online-softmax over precomputed S with R5's exact update text.
// Gated on ws_size (S needs 128MB); fallback = R5 k_mha verbatim. Also gated: ping-pong
// out/emb/ref buffers (drop k_copyback) and single-launch FFN via dedicated hidden buffer.
#define BB 4
#define DD 256

typedef unsigned long long u64;
typedef long long s64;
typedef unsigned int u32;

__device__ __forceinline__ float sigm(float x) { return 1.0f / (1.0f + expf(-x)); }

// ---------------- LayerNorm (D=256, one row per block of 256 threads) ----------------
__global__ void k_ln(const float* __restrict__ x, const float* __restrict__ w,
                     const float* __restrict__ b, float* __restrict__ ln) {
    int row = blockIdx.x, tid = threadIdx.x;
    float v = x[(size_t)row * DD + tid];
    __shared__ float sred[4];
    float s = v;
#pragma unroll
    for (int o = 32; o > 0; o >>= 1) s += __shfl_down(s, o);
    if ((tid & 63) == 0) sred[tid >> 6] = s;
    __syncthreads();
    float mu = (sred[0] + sred[1] + sred[2] + sred[3]) * (1.0f / 256.0f);
    __syncthreads();
    float d = v - mu;
    float s2 = d * d;
#pragma unroll
    for (int o = 32; o > 0; o >>= 1) s2 += __shfl_down(s2, o);
    if ((tid & 63) == 0) sred[tid >> 6] = s2;
    __syncthreads();
    float var = (sred[0] + sred[1] + sred[2] + sred[3]) * (1.0f / 256.0f);
    float r = rsqrtf(var + 1e-5f);
    ln[(size_t)row * DD + tid] = d * r * w[tid] + b[tid];
}

// ---------------- GEMM core: C[M,N] = act((A+Pe)[M,K] @ W[N,K]^T + bias) (+ residual) ----------
// 64x64 tile, BK=16, 256 threads, 4x4 microtile, double-buffered LDS (1 barrier/iter).
// Per-output-element chain: strict ascending-k single-fma (acc += a*w) — bit-identical to R0.
template <int ACT, int RES>
__device__ __forceinline__ void gemm_core(float (*As)[16][64], float (*Ws)[16][64],
                                          const float* __restrict__ A, const float* __restrict__ Pe, int pe,
                                          const float* __restrict__ W, const float* __restrict__ bias,
                                          const float* __restrict__ Rm, float* __restrict__ C,
                                          float* __restrict__ C2,
                                          int M, int N, int K, int row0, int col0) {
    int tid = threadIdx.x;
    int tx = tid & 15, ty = tid >> 4;
    int lm = tid >> 2, lk = (tid & 3) * 4;
    float acc[4][4] = {{0.f}};
    int ar = row0 + lm;
    const float* Arow = A + (size_t)ar * K + lk;
    const float* Prow = pe ? (Pe + (size_t)ar * K + lk) : nullptr;
    const float* Wrow = W + (size_t)(col0 + lm) * K + lk;  // N multiple of 64
    float4 av = make_float4(0.f, 0.f, 0.f, 0.f), wv;
    if (ar < M) {
        av = *(const float4*)(Arow);
        if (pe) { float4 pv = *(const float4*)(Prow); av.x += pv.x; av.y += pv.y; av.z += pv.z; av.w += pv.w; }
    }
    wv = *(const float4*)(Wrow);
    As[0][lk + 0][lm] = av.x; As[0][lk + 1][lm] = av.y; As[0][lk + 2][lm] = av.z; As[0][lk + 3][lm] = av.w;
    Ws[0][lk + 0][lm] = wv.x; Ws[0][lk + 1][lm] = wv.y; Ws[0][lk + 2][lm] = wv.z; Ws[0][lk + 3][lm] = wv.w;
    __syncthreads();
    int nb = K >> 4;
    for (int t = 0; t < nb; t++) {
        int cur = t & 1, nxt = cur ^ 1;
        bool more = (t + 1 < nb);
        if (more) {
            int k0 = (t + 1) << 4;
            av = make_float4(0.f, 0.f, 0.f, 0.f);
            if (ar < M) {
                av = *(const float4*)(Arow + k0);
                if (pe) { float4 pv = *(const float4*)(Prow + k0); av.x += pv.x; av.y += pv.y; av.z += pv.z; av.w += pv.w; }
            }
            wv = *(const float4*)(Wrow + k0);
        }
#pragma unroll
        for (int kk = 0; kk < 16; kk++) {
            float4 a = *(const float4*)&As[cur][kk][ty << 2];
            float4 w = *(const float4*)&Ws[cur][kk][tx << 2];
            acc[0][0] += a.x * w.x; acc[0][1] += a.x * w.y; acc[0][2] += a.x * w.z; acc[0][3] += a.x * w.w;
            acc[1][0] += a.y * w.x; acc[1][1] += a.y * w.y; acc[1][2] += a.y * w.z; acc[1][3] += a.y * w.w;
            acc[2][0] += a.z * w.x; acc[2][1] += a.z * w.y; acc[2][2] += a.z * w.z; acc[2][3] += a.z * w.w;
            acc[3][0] += a.w * w.x; acc[3][1] += a.w * w.y; acc[3][2] += a.w * w.z; acc[3][3] += a.w * w.w;
        }
        if (more) {
            As[nxt][lk + 0][lm] = av.x; As[nxt][lk + 1][lm] = av.y; As[nxt][lk + 2][lm] = av.z; As[nxt][lk + 3][lm] = av.w;
            Ws[nxt][lk + 0][lm] = wv.x; Ws[nxt][lk + 1][lm] = wv.y; Ws[nxt][lk + 2][lm] = wv.z; Ws[nxt][lk + 3][lm] = wv.w;
        }
        __syncthreads();
    }
#pragma unroll
    for (int i2 = 0; i2 < 4; i2++) {
        int r = row0 + (ty << 2) + i2;
        if (r >= M) continue;
        int cc = col0 + (tx << 2);
        float4 v;
        v.x = acc[i2][0] + bias[cc + 0];
        v.y = acc[i2][1] + bias[cc + 1];
        v.z = acc[i2][2] + bias[cc + 2];
        v.w = acc[i2][3] + bias[cc + 3];
        if (ACT == 1) { v.x = fmaxf(v.x, 0.f); v.y = fmaxf(v.y, 0.f); v.z = fmaxf(v.z, 0.f); v.w = fmaxf(v.w, 0.f); }
        if (RES == 1) {
            float4 rm = *(const float4*)(Rm + (size_t)r * N + cc);
            v.x += rm.x; v.y += rm.y; v.z += rm.z; v.w += rm.w;
        }
        *(float4*)(C + (size_t)r * N + cc) = v;
        if (C2) *(float4*)(C2 + (size_t)r * N + cc) = v;
    }
}

template <int ACT, int RES, int PE>
__global__ __launch_bounds__(256) void k_gemm(const float* __restrict__ A, const float* __restrict__ Pe,
                                              const float* __restrict__ W, const float* __restrict__ bias,
                                              const float* __restrict__ Rm, float* __restrict__ C,
                                              int M, int N, int K) {
    __shared__ float As[2][16][64];
    __shared__ float Ws[2][16][64];
    gemm_core<ACT, RES>(As, Ws, A, Pe, PE, W, bias, Rm, C, nullptr, M, N, K, blockIdx.y * 64, blockIdx.x * 64);
}

// FFN second GEMM with fused layer-output store (C2 = outf region; same values as C).
__global__ __launch_bounds__(256) void k_gemm_st2(const float* __restrict__ A, const float* __restrict__ W,
                                                  const float* __restrict__ bias, const float* __restrict__ Rm,
                                                  float* __restrict__ C, float* __restrict__ C2,
                                                  int M, int N, int K) {
    __shared__ float As[2][16][64];
    __shared__ float Ws[2][16][64];
    gemm_core<0, 1>(As, Ws, A, nullptr, 0, W, bias, Rm, C, C2, M, N, K, blockIdx.y * 64, blockIdx.x * 64);
}

// QKV merged: blockIdx.z in {0,1,2} picks weight block / bias / output; z<2 adds Pe.
__global__ __launch_bounds__(256) void k_gemm_qkv(const float* __restrict__ A, const float* __restrict__ Pe,
                                                  const float* __restrict__ Wqkv, const float* __restrict__ bqkv,
                                                  float* __restrict__ Cq, float* __restrict__ Ck, float* __restrict__ Cv,
                                                  int M, int K) {
    __shared__ float As[2][16][64];
    __shared__ float Ws[2][16][64];
    int z = blockIdx.z;
    const float* W = Wqkv + (size_t)z * 256 * K;
    const float* bias = bqkv + z * 256;
    float* C = (z == 0) ? Cq : (z == 1) ? Ck : Cv;
    gemm_core<0, 0>(As, Ws, A, Pe, (z < 2) ? 1 : 0, W, bias, nullptr, C, nullptr, M, 256, K,
                    blockIdx.y * 64, blockIdx.x * 64);
}

// off (N=256) + aw (N=128) merged: z picks; z=1 blocks with col0>=128 exit whole-block.
__global__ __launch_bounds__(256) void k_gemm_offaw(const float* __restrict__ A, const float* __restrict__ Pe,
                                                    const float* __restrict__ Woff, const float* __restrict__ boff,
                                                    const float* __restrict__ Waw, const float* __restrict__ baw,
                                                    float* __restrict__ Coff, float* __restrict__ Caw,
                                                    int M, int K) {
    __shared__ float As[2][16][64];
    __shared__ float Ws[2][16][64];
    int z = blockIdx.z;
    int N = (z == 0) ? 256 : 128;
    if ((int)(blockIdx.x * 64) >= N) return;  // uniform whole-block exit (before any barrier)
    gemm_core<0, 0>(As, Ws, A, Pe, 1, (z == 0) ? Woff : Waw, (z == 0) ? boff : baw, nullptr,
                    (z == 0) ? Coff : Caw, nullptr, M, N, K, blockIdx.y * 64, blockIdx.x * 64);
}

// ---------------- MHA dot macro (exact R3/R5 text; whole chain per thread) ----------------
#define MHA_DOT8(SREG, JJ)                                                       \
    {                                                                            \
        _Pragma("unroll")                                                        \
        for (int u = 0; u < 8; u++) SREG[u] = 0.f;                               \
        _Pragma("unroll")                                                        \
        for (int c4 = 0; c4 < 8; c4++) {                                         \
            float q0 = qv[c4 * 4 + 0], q1 = qv[c4 * 4 + 1];                      \
            float q2 = qv[c4 * 4 + 2], q3 = qv[c4 * 4 + 3];                      \
            _Pragma("unroll")                                                    \
            for (int u = 0; u < 8; u++) {                                        \
                float4 k4 = *(const float4*)&Ks[(JJ) + u][c4 * 4];               \
                SREG[u] += q0 * k4.x; SREG[u] += q1 * k4.y;                      \
                SREG[u] += q2 * k4.z; SREG[u] += q3 * k4.w;                      \
            }                                                                    \
        }                                                                        \
    }

// ---------------- score precompute: S[bh][j][q] = (Q*scale) . K, exact c-order per score --------
// Machine-filling parallel kernel. Each score chain lives whole in one thread with the exact
// MHA_DOT8 text and the exact qv-scale load text — bit-identical to the in-mha dots.
__global__ __launch_bounds__(64) void k_qk(const float* __restrict__ Qb, const float* __restrict__ Kb,
                                           float* __restrict__ S, int Qn) {
    int bh = blockIdx.z;
    int b = bh >> 3, h = bh & 7;
    int lane = threadIdx.x;
    int qi = blockIdx.x * 64 + lane;
    int j0 = blockIdx.y * 64;
    __shared__ float Ks[64][36];
    float qv[32];
    const float scale = 0.17677669529663687f;  // 1/sqrt(32)
    bool active = qi < Qn;
    if (active) {
        const float4* qp = (const float4*)(Qb + ((size_t)(b * Qn + qi)) * DD + h * 32);
#pragma unroll
        for (int c4 = 0; c4 < 8; c4++) {
            float4 t = qp[c4];
            qv[c4 * 4 + 0] = t.x * scale; qv[c4 * 4 + 1] = t.y * scale;
            qv[c4 * 4 + 2] = t.z * scale; qv[c4 * 4 + 3] = t.w * scale;
        }
    } else {
#pragma unroll
        for (int c = 0; c < 32; c++) qv[c] = 0.f;
    }
    int nj = Qn - j0; if (nj > 64) nj = 64;
    if (lane < nj) {
        const float4* kp = (const float4*)(Kb + ((size_t)(b * Qn + j0 + lane)) * DD + h * 32);
#pragma unroll
        for (int c4 = 0; c4 < 8; c4++) *(float4*)&Ks[lane][c4 * 4] = kp[c4];
    }
    __syncthreads();
    float* Sp = S + (size_t)bh * Qn * Qn;
    float scur[8];
    for (int g = 0; g < 8; g++) {
        int jj = g << 3;
        if (jj >= nj) break;  // wave-uniform
        MHA_DOT8(scur, jj)
#pragma unroll
        for (int u = 0; u < 8; u++) {
            int j = j0 + jj + u;
            if (active && j < Qn) Sp[(size_t)j * Qn + qi] = scur[u];
        }
    }
}

// ---------------- MHA serial pass over precomputed scores ----------------
// 1 query/thread, exact R5 phase A/B/C update text, consuming S values (bit-identical to the
// in-kernel dots) in exact j order. V staged in LDS (R4 lesson). S prefetched 1 group ahead.
__global__ __launch_bounds__(64) void k_mha_s(const float* __restrict__ S, const float* __restrict__ Vb,
                                              float* __restrict__ Ob, int Qn) {
    int bh = blockIdx.y;
    int b = bh >> 3, h = bh & 7;
    int lane = threadIdx.x;
    int qi = blockIdx.x * 64 + lane;
    __shared__ float Vs[64][36];
    float acc[32];
#pragma unroll
    for (int c = 0; c < 32; c++) acc[c] = 0.f;
    float m = -INFINITY, l = 0.f;
    bool active = qi < Qn;
    int qs = active ? qi : 0;  // inactive lanes read column 0 (valid memory, values unused)
    const float* Sq = S + (size_t)bh * Qn * Qn + qs;
    int ng = Qn >> 3;
    float scur[8], snxt[8];
#pragma unroll
    for (int u = 0; u < 8; u++) scur[u] = Sq[(size_t)u * Qn];  // group 0 (Qn >= 31 always)
    int gg = 0;
    for (int k0 = 0; k0 < Qn; k0 += 64) {
        int nk = Qn - k0; if (nk > 64) nk = 64;
        if (lane < nk) {
            const float4* vp = (const float4*)(Vb + ((size_t)(b * Qn + k0 + lane)) * DD + h * 32);
#pragma unroll
            for (int c4 = 0; c4 < 8; c4++) *(float4*)&Vs[lane][c4 * 4] = vp[c4];
        }
        __syncthreads();
        int gl = nk >> 3;
        for (int g2 = 0; g2 < gl; g2++, gg++) {
            int jj = g2 << 3;  // local V index base
            bool morep = (gg + 1 < ng);
            if (morep) {
                const float* Sn = Sq + (size_t)(k0 + jj + 8) * Qn;
#pragma unroll
                for (int u = 0; u < 8; u++) snxt[u] = Sn[(size_t)u * Qn];
            }
            // --- phase A: m-chain (exact R5 text) ---
            float mch[9];
            mch[0] = m;
#pragma unroll
            for (int u = 0; u < 8; u++) mch[u + 1] = fmaxf(mch[u], scur[u]);
            // --- phase B: 8 independent expf, then serial l-chain (exact R5 text) ---
            float e8[8];
#pragma unroll
            for (int u = 0; u < 8; u++) e8[u] = expf(fminf(mch[u] - scur[u], scur[u] - mch[u]));
            float sc8[8], p8[8];
#pragma unroll
            for (int u = 0; u < 8; u++) {
                bool gt = scur[u] > mch[u];
                sc8[u] = gt ? e8[u] : 1.0f;
                p8[u] = gt ? 1.0f : e8[u];
                l = l * sc8[u] + p8[u];
            }
            m = mch[8];
            // --- phase C: acc sweeps in exact u order; V one-key register prefetch ---
            float4 vc[8], vn[8];
#pragma unroll
            for (int c4 = 0; c4 < 8; c4++) vc[c4] = *(const float4*)&Vs[jj][c4 * 4];
#pragma unroll
            for (int u = 0; u < 8; u++) {
                if (u < 7) {
#pragma unroll
                    for (int c4 = 0; c4 < 8; c4++) vn[c4] = *(const float4*)&Vs[jj + u + 1][c4 * 4];
                }
                float sc = sc8[u], p = p8[u];
#pragma unroll
                for (int c4 = 0; c4 < 8; c4++) {
                    acc[c4 * 4 + 0] = acc[c4 * 4 + 0] * sc + p * vc[c4].x;
                    acc[c4 * 4 + 1] = acc[c4 * 4 + 1] * sc + p * vc[c4].y;
                    acc[c4 * 4 + 2] = acc[c4 * 4 + 2] * sc + p * vc[c4].z;
                    acc[c4 * 4 + 3] = acc[c4 * 4 + 3] * sc + p * vc[c4].w;
                }
                if (u < 7) {
#pragma unroll
                    for (int c4 = 0; c4 < 8; c4++) vc[c4] = vn[c4];
                }
            }
            if (morep) {
#pragma unroll
                for (int u = 0; u < 8; u++) scur[u] = snxt[u];
            }
        }
        for (int j = gl << 3; j < nk; j++) {  // tail keys (last tile only)
            float sv = Sq[(size_t)(k0 + j) * Qn];
            float mn = fmaxf(m, sv);
            float e = expf(fminf(m - sv, sv - m));
            bool gt = sv > m;
            float sc = gt ? e : 1.0f;
            float p = gt ? 1.0f : e;
            l = l * sc + p;
            m = mn;
#pragma unroll
            for (int c4 = 0; c4 < 8; c4++) {
                float4 v4 = *(const float4*)&Vs[j][c4 * 4];
                acc[c4 * 4 + 0] = acc[c4 * 4 + 0] * sc + p * v4.x;
                acc[c4 * 4 + 1] = acc[c4 * 4 + 1] * sc + p * v4.y;
                acc[c4 * 4 + 2] = acc[c4 * 4 + 2] * sc + p * v4.z;
                acc[c4 * 4 + 3] = acc[c4 * 4 + 3] * sc + p * v4.w;
            }
        }
        __syncthreads();
    }
    if (active) {
        float inv = 1.0f / l;
        float* op = Ob + ((size_t)(b * Qn + qi)) * DD + h * 32;
#pragma unroll
        for (int c4 = 0; c4 < 8; c4++) {
            float4 o;
            o.x = acc[c4 * 4 + 0] * inv; o.y = acc[c4 * 4 + 1] * inv;
            o.z = acc[c4 * 4 + 2] * inv; o.w = acc[c4 * 4 + 3] * inv;
            *(float4*)(op + c4 * 4) = o;
        }
    }
}

// ---------------- MHA fallback (R5 verbatim; used when workspace too small) ----------------
__global__ __launch_bounds__(64) void k_mha(const float* __restrict__ Qb, const float* __restrict__ Kb,
                                            const float* __restrict__ Vb, float* __restrict__ Ob, int Qn) {
    int bh = blockIdx.y;
    int b = bh >> 3, h = bh & 7;
    int lane = threadIdx.x;
    int qi = blockIdx.x * 64 + lane;
    __shared__ float Ks[64][36];
    __shared__ float Vs[64][36];
    float qv[32];
    float acc[32];
#pragma unroll
    for (int c = 0; c < 32; c++) acc[c] = 0.f;
    float m = -INFINITY, l = 0.f;
    const float scale = 0.17677669529663687f;
    bool active = qi < Qn;
    if (active) {
        const float4* qp = (const float4*)(Qb + ((size_t)(b * Qn + qi)) * DD + h * 32);
#pragma unroll
        for (int c4 = 0; c4 < 8; c4++) {
            float4 t = qp[c4];
            qv[c4 * 4 + 0] = t.x * scale; qv[c4 * 4 + 1] = t.y * scale;
            qv[c4 * 4 + 2] = t.z * scale; qv[c4 * 4 + 3] = t.w * scale;
        }
    } else {
#pragma unroll
        for (int c = 0; c < 32; c++) qv[c] = 0.f;
    }
    for (int k0 = 0; k0 < Qn; k0 += 64) {
        int nk = Qn - k0; if (nk > 64) nk = 64;
        if (lane < nk) {
            const float4* kp = (const float4*)(Kb + ((size_t)(b * Qn + k0 + lane)) * DD + h * 32);
            const float4* vp = (const float4*)(Vb + ((size_t)(b * Qn + k0 + lane)) * DD + h * 32);
#pragma unroll
            for (int c4 = 0; c4 < 8; c4++) {
                *(float4*)&Ks[lane][c4 * 4] = kp[c4];
                *(float4*)&Vs[lane][c4 * 4] = vp[c4];
            }
        }
        __syncthreads();
        int ng = nk >> 3;
        float scur[8], snxt[8];
        if (ng > 0) MHA_DOT8(scur, 0)
        for (int g = 0; g < ng; g++) {
            int jj = g << 3;
            bool morep = (g + 1 < ng);
            if (morep) MHA_DOT8(snxt, jj + 8)
            float mch[9];
            mch[0] = m;
#pragma unroll
            for (int u = 0; u < 8; u++) mch[u + 1] = fmaxf(mch[u], scur[u]);
            float e8[8];
#pragma unroll
            for (int u = 0; u < 8; u++) e8[u] = expf(fminf(mch[u] - scur[u], scur[u] - mch[u]));
            float sc8[8], p8[8];
#pragma unroll
            for (int u = 0; u < 8; u++) {
                bool gt = scur[u] > mch[u];
                sc8[u] = gt ? e8[u] : 1.0f;
                p8[u] = gt ? 1.0f : e8[u];
                l = l * sc8[u] + p8[u];
            }
            m = mch[8];
            float4 vc[8], vn[8];
#pragma unroll
            for (int c4 = 0; c4 < 8; c4++) vc[c4] = *(const float4*)&Vs[jj][c4 * 4];
#pragma unroll
            for (int u = 0; u < 8; u++) {
                if (u < 7) {
#pragma unroll
                    for (int c4 = 0; c4 < 8; c4++) vn[c4] = *(const float4*)&Vs[jj + u + 1][c4 * 4];
                }
                float sc = sc8[u], p = p8[u];
#pragma unroll
                for (int c4 = 0; c4 < 8; c4++) {
                    acc[c4 * 4 + 0] = acc[c4 * 4 + 0] * sc + p * vc[c4].x;
                    acc[c4 * 4 + 1] = acc[c4 * 4 + 1] * sc + p * vc[c4].y;
                    acc[c4 * 4 + 2] = acc[c4 * 4 + 2] * sc + p * vc[c4].z;
                    acc[c4 * 4 + 3] = acc[c4 * 4 + 3] * sc + p * vc[c4].w;
                }
                if (u < 7) {
#pragma unroll
                    for (int c4 = 0; c4 < 8; c4++) vc[c4] = vn[c4];
                }
            }
            if (morep) {
#pragma unroll
                for (int u = 0; u < 8; u++) scur[u] = snxt[u];
            }
        }
        for (int j = ng << 3; j < nk; j++) {
            float sv = 0.f;
#pragma unroll
            for (int c4 = 0; c4 < 8; c4++) {
                float4 k4 = *(const float4*)&Ks[j][c4 * 4];
                sv += qv[c4 * 4 + 0] * k4.x; sv += qv[c4 * 4 + 1] * k4.y;
                sv += qv[c4 * 4 + 2] * k4.z; sv += qv[c4 * 4 + 3] * k4.w;
            }
            float mn = fmaxf(m, sv);
            float e = expf(fminf(m - sv, sv - m));
            bool gt = sv > m;
            float sc = gt ? e : 1.0f;
            float p = gt ? 1.0f : e;
            l = l * sc + p;
            m = mn;
#pragma unroll
            for (int c4 = 0; c4 < 8; c4++) {
                float4 v4 = *(const float4*)&Vs[j][c4 * 4];
                acc[c4 * 4 + 0] = acc[c4 * 4 + 0] * sc + p * v4.x;
                acc[c4 * 4 + 1] = acc[c4 * 4 + 1] * sc + p * v4.y;
                acc[c4 * 4 + 2] = acc[c4 * 4 + 2] * sc + p * v4.z;
                acc[c4 * 4 + 3] = acc[c4 * 4 + 3] * sc + p * v4.w;
            }
        }
        __syncthreads();
    }
    if (active) {
        float inv = 1.0f / l;
        float* op = Ob + ((size_t)(b * Qn + qi)) * DD + h * 32;
#pragma unroll
        for (int c4 = 0; c4 < 8; c4++) {
            float4 o;
            o.x = acc[c4 * 4 + 0] * inv; o.y = acc[c4 * 4 + 1] * inv;
            o.z = acc[c4 * 4 + 2] * inv; o.w = acc[c4 * 4 + 3] * inv;
            *(float4*)(op + c4 * 4) = o;
        }
    }
}

// ---------------- feature transpose: [b][c=256][H][W] -> [b][h][H*W][hd=32] ----------------
__global__ __launch_bounds__(256) void k_trfeat(const float* __restrict__ in, float* __restrict__ out, int HH) {
    __shared__ float t[32][65];
    int bh = blockIdx.y;             // b*8 + h
    int b = bh >> 3, h = bh & 7;
    int s0 = blockIdx.x * 64;
    int tid = threadIdx.x;
    const float* ip = in + ((size_t)(b * 256 + h * 32)) * HH + s0;
#pragma unroll
    for (int i = 0; i < 8; i++) {
        int idx = i * 256 + tid;
        int c = idx >> 6, s = idx & 63;
        t[c][s] = ip[(size_t)c * HH + s];
    }
    __syncthreads();
    float* op = out + ((size_t)bh * HH + s0) * 32;
#pragma unroll
    for (int i = 0; i < 8; i++) {
        int idx = i * 256 + tid;
        int s = idx >> 5, c = idx & 31;
        op[(size_t)s * 32 + c] = t[c][s];
    }
}

// ---------------- deformable sampling ----------------
__device__ __forceinline__ float d_samp(const float* fp, int W, int H, int x, int y) {
    if (x < 0 || x > W - 1 || y < 0 || y > H - 1) return 0.f;
    return fp[y * W + x];
}
__device__ __forceinline__ float d_bil(const float* fp, int W, int H, float gx, float gy) {
    float fx = (gx + 1.0f) * 0.5f * (float)(W - 1);
    float fy = (gy + 1.0f) * 0.5f * (float)(H - 1);
    float x0f = floorf(fx), y0f = floorf(fy);
    int x0 = (int)x0f, y0 = (int)y0f;
    float wx = fx - x0f, wy = fy - y0f;
    float v00 = d_samp(fp, W, H, x0, y0);
    float v10 = d_samp(fp, W, H, x0 + 1, y0);
    float v01 = d_samp(fp, W, H, x0, y0 + 1);
    float v11 = d_samp(fp, W, H, x0 + 1, y0 + 1);
    return v00 * (1.f - wx) * (1.f - wy) + v10 * wx * (1.f - wy) + v01 * (1.f - wx) * wy + v11 * wx * wy;
}
__device__ __forceinline__ float d_samp32(const float* fp, int W, int H, int x, int y) {
    if (x < 0 || x > W - 1 || y < 0 || y > H - 1) return 0.f;
    return fp[(size_t)(y * W + x) * 32];
}
__device__ __forceinline__ float d_bil32(const float* fp, int W, int H, float gx, float gy) {
    float fx = (gx + 1.0f) * 0.5f * (float)(W - 1);
    float fy = (gy + 1.0f) * 0.5f * (float)(H - 1);
    float x0f = floorf(fx), y0f = floorf(fy);
    int x0 = (int)x0f, y0 = (int)y0f;
    float wx = fx - x0f, wy = fy - y0f;
    float v00 = d_samp32(fp, W, H, x0, y0);
    float v10 = d_samp32(fp, W, H, x0 + 1, y0);
    float v01 = d_samp32(fp, W, H, x0, y0 + 1);
    float v11 = d_samp32(fp, W, H, x0 + 1, y0 + 1);
    return v00 * (1.f - wx) * (1.f - wy) + v10 * wx * (1.f - wy) + v01 * (1.f - wx) * wy + v11 * wx * wy;
}

template <int TR>
__global__ __launch_bounds__(256) void k_deform(const float* __restrict__ offL, const float* __restrict__ awL,
                                                const float* __restrict__ ref,
                                                const float* __restrict__ f0, const float* __restrict__ f1,
                                                const float* __restrict__ f2, const float* __restrict__ f3,
                                                float* __restrict__ caf, float* __restrict__ attn_out,
                                                int Qn) {
    int row = blockIdx.x;  // b*Qn + q
    int b = row / Qn;
    int tid = threadIdx.x;
    __shared__ float attn_s[8][16];
    __shared__ float off_s[8][16][2];
    __shared__ float rxy[2];
    if (tid < 8) {
        int h = tid;
        const float* ap = awL + (size_t)row * 128 + h * 16;
        float mx = -INFINITY;
        float e[16];
#pragma unroll
        for (int j = 0; j < 16; j++) mx = fmaxf(mx, ap[j]);
        float ssum = 0.f;
#pragma unroll
        for (int j = 0; j < 16; j++) { e[j] = expf(ap[j] - mx); ssum += e[j]; }
        float inv = 1.0f / ssum;
        float* ao = attn_out + (size_t)row * 128 + h * 16;
#pragma unroll
        for (int j = 0; j < 16; j++) {
            float p = e[j] * inv;
            attn_s[h][j] = p;
            ao[j] = p;
        }
        const float* op = offL + (size_t)row * 256 + h * 32;
#pragma unroll
        for (int j = 0; j < 16; j++) {
            off_s[h][j][0] = tanhf(op[j * 2 + 0]);
            off_s[h][j][1] = tanhf(op[j * 2 + 1]);
        }
    }
    if (tid == 8) {
        rxy[0] = ref[(size_t)row * 2 + 0] * 2.f - 1.f;
        rxy[1] = ref[(size_t)row * 2 + 1] * 2.f - 1.f;
    }
    __syncthreads();
    int h = tid >> 5, c = tid & 31;
    float agg = 0.f;
#pragma unroll
    for (int l = 0; l < 4; l++) {
        const int H = 128 >> l;
        const float* base = (l == 0 ? f0 : l == 1 ? f1 : l == 2 ? f2 : f3);
        const float* fp;
        if (TR) fp = base + ((size_t)(b * 8 + h) * (H * H)) * 32 + c;
        else    fp = base + (size_t)(b * DD + h * 32 + c) * H * H;
#pragma unroll
        for (int p = 0; p < 4; p++) {
            int j = l * 4 + p;
            float sv;
            if (TR) sv = d_bil32(fp, H, H, rxy[0] + off_s[h][j][0], rxy[1] + off_s[h][j][1]);
            else    sv = d_bil(fp, H, H, rxy[0] + off_s[h][j][0], rxy[1] + off_s[h][j][1]);
            agg += attn_s[h][j] * sv;
        }
    }
    caf[(size_t)row * DD + h * 32 + c] = agg;
}

// ---------------- small per-row 2-output heads ----------------
__global__ __launch_bounds__(64) void k_refinit(const float* __restrict__ hbuf, const float* __restrict__ w2,
                                                const float* __restrict__ b2, float* __restrict__ ref) {
    int row = blockIdx.x, lane = threadIdx.x;
    const float* hp = hbuf + (size_t)row * DD;
    float s0 = 0.f, s1 = 0.f;
#pragma unroll
    for (int d = 0; d < 4; d++) {
        int dd = lane + d * 64;
        float v = hp[dd];
        s0 += v * w2[dd];
        s1 += v * w2[DD + dd];
    }
#pragma unroll
    for (int o = 32; o > 0; o >>= 1) { s0 += __shfl_down(s0, o); s1 += __shfl_down(s1, o); }
    if (lane == 0) {
        ref[(size_t)row * 2 + 0] = sigm(s0 + b2[0]);
        ref[(size_t)row * 2 + 1] = sigm(s1 + b2[1]);
    }
}

// refine + score fused (chains identical to R0's k_refine / k_score).
__global__ __launch_bounds__(64) void k_refsc(const float* __restrict__ out, const float* __restrict__ rw,
                                              const float* __restrict__ rb, float* __restrict__ ref,
                                              const float* __restrict__ sw, const float* __restrict__ sb,
                                              float* __restrict__ score) {
    int row = blockIdx.x, lane = threadIdx.x;
    const float* op = out + (size_t)row * DD;
    float s0 = 0.f, s1 = 0.f;
#pragma unroll
    for (int d = 0; d < 4; d++) {
        int dd = lane + d * 64;
        float v = op[dd];
        s0 += v * rw[dd];
        s1 += v * rw[DD + dd];
    }
#pragma unroll
    for (int o = 32; o > 0; o >>= 1) { s0 += __shfl_down(s0, o); s1 += __shfl_down(s1, o); }
    if (lane == 0) {
        float r0 = ref[(size_t)row * 2 + 0] + tanhf(s0 + rb[0]) * 0.5f;
        float r1 = ref[(size_t)row * 2 + 1] + tanhf(s1 + rb[1]) * 0.5f;
        ref[(size_t)row * 2 + 0] = fminf(fmaxf(r0, 0.f), 1.f);
        ref[(size_t)row * 2 + 1] = fminf(fmaxf(r1, 0.f), 1.f);
        float s = sb[0];
        for (int d = 0; d < DD; d++) s += op[d] * sw[d];
        score[row] = sigm(s);
    }
}

// ---------------- top-k (exact jax.lax.top_k: desc value, asc index on ties) ----------------
__global__ __launch_bounds__(256) void k_topk(const float* __restrict__ score, int* __restrict__ idx,
                                              int Qn, int PAD, int keep) {
    __shared__ u64 keys[1024];
    int b = blockIdx.x, tid = threadIdx.x;
    for (int q = tid; q < PAD; q += 256) {
        u64 key;
        if (q < Qn) {
            u32 u = __float_as_uint(score[b * Qn + q]);
            u = (u & 0x80000000u) ? ~u : (u | 0x80000000u);
            u32 hi = ~u;
            key = (((u64)hi) << 32) | (u32)q;
        } else {
            key = 0xFFFFFFFFFFFFFFFFULL;
        }
        keys[q] = key;
    }
    __syncthreads();
    for (int k = 2; k <= PAD; k <<= 1) {
        for (int j = k >> 1; j > 0; j >>= 1) {
            for (int i = tid; i < PAD; i += 256) {
                int ij = i ^ j;
                if (ij > i) {
                    bool up = ((i & k) == 0);
                    u64 a = keys[i], c = keys[ij];
                    if ((a > c) == up) { keys[i] = c; keys[ij] = a; }
                }
            }
            __syncthreads();
        }
    }
    for (int t = tid; t < keep; t += 256) idx[b * keep + t] = (int)(keys[t] & 0xFFFFFFFFu);
}

__global__ __launch_bounds__(256) void k_gather(const float* __restrict__ osrc, const float* __restrict__ esrc,
                                                const float* __restrict__ rsrc, const int* __restrict__ idx,
                                                float* __restrict__ oT, float* __restrict__ eT,
                                                float* __restrict__ rT, int Qin, int keep) {
    int j = blockIdx.x;
    int b = j / keep;
    int src = idx[j];
    int tid = threadIdx.x;
    size_t srow = (size_t)(b * Qin + src), drow = (size_t)j;
    oT[drow * DD + tid] = osrc[srow * DD + tid];
    eT[drow * DD + tid] = esrc[srow * DD + tid];
    if (tid < 2) rT[drow * 2 + tid] = rsrc[srow * 2 + tid];
}

__global__ __launch_bounds__(256) void k_copyback(const float* __restrict__ oT, const float* __restrict__ eT,
                                                  const float* __restrict__ rT, float* __restrict__ o,
                                                  float* __restrict__ e, float* __restrict__ r) {
    int row = blockIdx.x, tid = threadIdx.x;
    o[(size_t)row * DD + tid] = oT[(size_t)row * DD + tid];
    e[(size_t)row * DD + tid] = eT[(size_t)row * DD + tid];
    if (tid < 2) r[(size_t)row * 2 + tid] = rT[(size_t)row * 2 + tid];
}

// =======================================================================================
extern "C" void kernel_launch(void* const* d_in, const int* in_sizes, int n_in,
                              void* d_out, int out_size, void* d_ws, size_t ws_size,
                              hipStream_t stream) {
    (void)in_sizes; (void)n_in; (void)out_size;
    const float* q_obj = (const float*)d_in[0];
    const float* q_emb = (const float*)d_in[1];
    const float* feat0 = (const float*)d_in[2];
    const float* feat1 = (const float*)d_in[3];
    const float* feat2 = (const float*)d_in[4];
    const float* feat3 = (const float*)d_in[5];
    const float* sa_in_w = (const float*)d_in[6];
    const float* sa_in_b = (const float*)d_in[7];
    const float* sa_out_w = (const float*)d_in[8];
    const float* sa_out_b = (const float*)d_in[9];
    const float* off_w = (const float*)d_in[10];
    const float* off_b = (const float*)d_in[11];
    const float* aw_w = (const float*)d_in[12];
    const float* aw_b = (const float*)d_in[13];
    const float* ca_out_w = (const float*)d_in[14];
    const float* ca_out_b = (const float*)d_in[15];
    const float* ff_w1 = (const float*)d_in[16];
    const float* ff_b1 = (const float*)d_in[17];
    const float* ff_w2 = (const float*)d_in[18];
    const float* ff_b2 = (const float*)d_in[19];
    const float* nsa_w = (const float*)d_in[20];
    const float* nsa_b = (const float*)d_in[21];
    const float* nca_w = (const float*)d_in[22];
    const float* nca_b = (const float*)d_in[23];
    const float* nff_w = (const float*)d_in[24];
    const float* nff_b = (const float*)d_in[25];
    const float* ref_w1 = (const float*)d_in[26];
    const float* ref_b1 = (const float*)d_in[27];
    const float* ref_w2 = (const float*)d_in[28];
    const float* ref_b2 = (const float*)d_in[29];
    const float* score_w = (const float*)d_in[30];
    const float* score_b = (const float*)d_in[31];
    const float* refine_w = (const float*)d_in[32];
    const float* refine_b = (const float*)d_in[33];

    float* outf = (float*)d_out;
    float* ws = (float*)d_ws;
    const int RD = 4000 * 256;  // 1,024,000 floats
    float* f_out = ws;
    float* f_emb = ws + RD;
    float* f_ln  = ws + 2 * RD;
    float* sc0   = ws + 3 * RD;
    float* sc1   = ws + 4 * RD;
    float* sc2   = ws + 5 * RD;
    float* f_ref = ws + 6 * RD;                      // 8000 floats
    float* f_sc  = ws + 6 * RD + 8000;               // 4000 floats
    int*   i_idx = (int*)(ws + 6 * RD + 12032);      // 2000 ints
    float* f_tr  = ws + 6 * RD + 16384;              // transposed feats: 22,282,240 floats
    static const s64 tr_ofs[4] = {0, 16777216, 20971520, 22020096};
    const size_t tr_need_bytes = ((size_t)(6 * RD + 16384) + 22282240ULL) * 4ULL;
    const bool use_tr = ws_size >= tr_need_bytes;
    // extended region: Sbuf (32M) + f_hid (4.096M) + ping-pong out/emb/ref
    float* Sbuf   = f_tr + 22282240;        // ws + 28,442,624 floats
    float* f_hid  = Sbuf + 32000000;
    float* f_out2 = f_hid + 4096000;
    float* f_emb2 = f_out2 + 1024000;
    float* f_ref2 = f_emb2 + 1024000;
    const size_t ext_need_bytes = ((size_t)28442624ULL + 32000000ULL + 4096000ULL + 1024000ULL + 1024000ULL + 8000ULL) * 4ULL;
    const bool use_ext = use_tr && (ws_size >= ext_need_bytes);

    static const int Qs[6] = {1000, 500, 250, 125, 62, 31};
    static const s64 out_ofs[6] = {0, 1024000, 1536000, 1792000, 1920000, 1983488};
    static const s64 attn_ofs[6] = {2015232, 2527232, 2783232, 2911232, 2975232, 3006976};

    hipMemcpyAsync(f_out, q_obj, (size_t)RD * 4, hipMemcpyDeviceToDevice, stream);
    hipMemcpyAsync(f_emb, q_emb, (size_t)RD * 4, hipMemcpyDeviceToDevice, stream);

    if (use_tr) {
        k_trfeat<<<dim3(16384 / 64, 32), 256, 0, stream>>>(feat0, f_tr + tr_ofs[0], 16384);
        k_trfeat<<<dim3(4096 / 64, 32), 256, 0, stream>>>(feat1, f_tr + tr_ofs[1], 4096);
        k_trfeat<<<dim3(1024 / 64, 32), 256, 0, stream>>>(feat2, f_tr + tr_ofs[2], 1024);
        k_trfeat<<<dim3(256 / 64, 32), 256, 0, stream>>>(feat3, f_tr + tr_ofs[3], 256);
    }

    // initial reference points
    k_gemm<1, 0, 0><<<dim3(4, 63), 256, 0, stream>>>(f_emb, nullptr, ref_w1, ref_b1, nullptr, f_ln, 4000, 256, 256);
    k_refinit<<<4000, 64, 0, stream>>>(f_ln, ref_w2, ref_b2, f_ref);

    float* po = f_out; float* pe = f_emb; float* pr = f_ref;   // current buffers
    float* qo = f_out2; float* qe = f_emb2; float* qr = f_ref2; // ping-pong partners

    for (int i = 0; i < 6; i++) {
        const int Q = Qs[i];
        const int R = BB * Q;
        const int gy = (R + 63) / 64;
        const float* siw = sa_in_w + (size_t)i * 768 * 256;
        const float* sib = sa_in_b + (size_t)i * 768;

        // ---- self attention ----
        k_ln<<<R, 256, 0, stream>>>(po, nsa_w + i * 256, nsa_b + i * 256, f_ln);
        k_gemm_qkv<<<dim3(4, gy, 3), 256, 0, stream>>>(f_ln, pe, siw, sib, sc0, sc1, sc2, R, 256);
        if (use_ext) {
            int qt = (Q + 63) / 64;
            k_qk<<<dim3(qt, qt, 32), 64, 0, stream>>>(sc0, sc1, Sbuf, Q);
            k_mha_s<<<dim3(qt, 32), 64, 0, stream>>>(Sbuf, sc2, f_ln, Q);
        } else {
            k_mha<<<dim3((Q + 63) / 64, 32), 64, 0, stream>>>(sc0, sc1, sc2, f_ln, Q);
        }
        k_gemm<0, 1, 0><<<dim3(4, gy), 256, 0, stream>>>(f_ln, nullptr, sa_out_w + (size_t)i * 65536,
                                                         sa_out_b + i * 256, po, po, R, 256, 256);

        // ---- deformable cross attention ----
        k_ln<<<R, 256, 0, stream>>>(po, nca_w + i * 256, nca_b + i * 256, f_ln);
        k_gemm_offaw<<<dim3(4, gy, 2), 256, 0, stream>>>(f_ln, pe, off_w + (size_t)i * 65536, off_b + i * 256,
                                                         aw_w + (size_t)i * 32768, aw_b + i * 128, sc0, sc1, R, 256);
        if (use_tr)
            k_deform<1><<<R, 256, 0, stream>>>(sc0, sc1, pr, f_tr + tr_ofs[0], f_tr + tr_ofs[1],
                                               f_tr + tr_ofs[2], f_tr + tr_ofs[3], sc2, outf + attn_ofs[i], Q);
        else
            k_deform<0><<<R, 256, 0, stream>>>(sc0, sc1, pr, feat0, feat1, feat2, feat3, sc2,
                                               outf + attn_ofs[i], Q);
        k_gemm<0, 1, 0><<<dim3(4, gy), 256, 0, stream>>>(sc2, nullptr, ca_out_w + (size_t)i * 65536,
                                                         ca_out_b + i * 256, po, po, R, 256, 256);

        // ---- FFN; 2nd GEMM fuses layer store ----
        k_ln<<<R, 256, 0, stream>>>(po, nff_w + i * 256, nff_b + i * 256, f_ln);
        if (use_ext) {
            k_gemm<1, 0, 0><<<dim3(16, gy), 256, 0, stream>>>(f_ln, nullptr,
                                                              ff_w1 + (size_t)i * 262144, ff_b1 + i * 1024,
                                                              nullptr, f_hid, R, 1024, 256);
            k_gemm_st2<<<dim3(4, gy), 256, 0, stream>>>(f_hid, ff_w2 + (size_t)i * 262144,
                                                        ff_b2 + i * 256, po, po,
                                                        outf + out_ofs[i], R, 256, 1024);
        } else {
            for (int r0 = 0; r0 < R; r0 += 2000) {
                int mc = R - r0; if (mc > 2000) mc = 2000;
                int gyc = (mc + 63) / 64;
                k_gemm<1, 0, 0><<<dim3(16, gyc), 256, 0, stream>>>(f_ln + (size_t)r0 * 256, nullptr,
                                                                   ff_w1 + (size_t)i * 262144, ff_b1 + i * 1024,
                                                                   nullptr, sc0, mc, 1024, 256);
                k_gemm_st2<<<dim3(4, gyc), 256, 0, stream>>>(sc0, ff_w2 + (size_t)i * 262144,
                                                             ff_b2 + i * 256, po + (size_t)r0 * 256,
                                                             po + (size_t)r0 * 256,
                                                             outf + out_ofs[i] + (size_t)r0 * 256, mc, 256, 1024);
            }
        }

        // ---- refine + score, top-k select + gather ----
        if (i < 5) {
            int keep = Qs[i + 1];
            int PAD = 1;
            while (PAD < Q) PAD <<= 1;
            k_refsc<<<R, 64, 0, stream>>>(po, refine_w, refine_b, pr, score_w, score_b, f_sc);
            k_topk<<<4, 256, 0, stream>>>(f_sc, i_idx, Q, PAD, keep);
            if (use_ext) {
                k_gather<<<4 * keep, 256, 0, stream>>>(po, pe, pr, i_idx, qo, qe, qr, Q, keep);
                float* t;
                t = po; po = qo; qo = t;
                t = pe; pe = qe; qe = t;
                t = pr; pr = qr; qr = t;
            } else {
                k_gather<<<4 * keep, 256, 0, stream>>>(po, pe, pr, i_idx, sc0, sc1, sc2, Q, keep);
                k_copyback<<<4 * keep, 256, 0, stream>>>(sc0, sc1, sc2, po, pe, pr);
            }
        }
    }
}